// Round 1
// baseline (311.111 us; speedup 1.0000x reference)
//
#include <hip/hip_runtime.h>
#include <hip/hip_bf16.h>
#include <stdint.h>

#define B_ 2
#define N_ 2048
#define D_ 1024
#define H_ 16
#define HD_ 64
#define INNER_ 1024
#define HALF_W 128

typedef unsigned short u16;
typedef __attribute__((ext_vector_type(8))) short short8;
typedef __attribute__((ext_vector_type(4))) float floatx4;

// ---- bf16 <-> f32 bit helpers (RNE, no __hip_bfloat16 struct headaches) ----
__device__ inline u16 f2bu(float x) {
    union { float f; uint32_t u; } c; c.f = x;
    uint32_t u = c.u;
    uint32_t r = (u + 0x7FFFu + ((u >> 16) & 1u)) >> 16;
    return (u16)r;
}
__device__ inline float bu2f(u16 v) {
    union { float f; uint32_t u; } c; c.u = ((uint32_t)v) << 16;
    return c.f;
}

// =====================  convert x: fp32 -> bf16  =====================
__global__ __launch_bounds__(256) void k_convert_x(const float* __restrict__ x,
                                                   u16* __restrict__ xb, int n) {
    int i = (blockIdx.x * 256 + threadIdx.x) * 4;
    if (i < n) {
        float4 v = *(const float4*)(x + i);
        uint32_t p0 = (uint32_t)f2bu(v.x) | ((uint32_t)f2bu(v.y) << 16);
        uint32_t p1 = (uint32_t)f2bu(v.z) | ((uint32_t)f2bu(v.w) << 16);
        uint2 o; o.x = p0; o.y = p1;
        *(uint2*)(xb + i) = o;
    }
}

// ============  transpose+convert W: fp32 [1024][1024] -> bf16 [n][k]  ============
__global__ __launch_bounds__(256) void k_transpose_w(const float* __restrict__ src,
                                                     u16* __restrict__ dst) {
    __shared__ float ts[64][65];
    const int kb = blockIdx.x, nb = blockIdx.y;
    const int t = threadIdx.x;
    const int row = t >> 2;          // k-local 0..63
    const int c4 = (t & 3) * 16;     // n-local col start
    const float* s = src + (size_t)(kb * 64 + row) * 1024 + nb * 64 + c4;
#pragma unroll
    for (int i = 0; i < 16; i += 4) {
        float4 v = *(const float4*)(s + i);
        ts[row][c4 + i] = v.x; ts[row][c4 + i + 1] = v.y;
        ts[row][c4 + i + 2] = v.z; ts[row][c4 + i + 3] = v.w;
    }
    __syncthreads();
    const int n = row;               // n-local
    u16* d = dst + (size_t)(nb * 64 + n) * 1024 + kb * 64 + c4;
    u16 tmp[16];
#pragma unroll
    for (int i = 0; i < 16; ++i) tmp[i] = f2bu(ts[c4 + i][n]);
    *(uint4*)(d) = *(uint4*)tmp;
    *(uint4*)(d + 8) = *((uint4*)tmp + 1);
}

// =====================  pack biases  =====================
__global__ void k_pack_bias(const float* bq, const float* bk, const float* bv,
                            const float* bo, float* bias_qkv, float* bias_o) {
    int i = blockIdx.x * 256 + threadIdx.x;
    if (i < 1024) {
        bias_qkv[i] = bq[i];
        bias_qkv[1024 + i] = bk[i];
        bias_qkv[2048 + i] = bv[i];
        bias_o[i] = bo[i];
    }
}

// =====================  bf16 MFMA GEMM: C = A[M][K] * Bt[N][K]^T + bias  =====================
// block 256 = 4 waves, tile 128x128, BK=64; wave -> 64x64 (4x4 mfma_16x16x32 accs)
__global__ __launch_bounds__(256) void k_gemm_bt(const u16* __restrict__ A,
                                                 const u16* __restrict__ Bt,
                                                 const float* __restrict__ bias,
                                                 void* __restrict__ C,
                                                 int M, int N, int K, int store_bf16) {
    __shared__ u16 As[128 * 72];
    __shared__ u16 Bs[128 * 72];
    const int t = threadIdx.x;
    const int wave = t >> 6, lane = t & 63;
    const int quad = lane >> 4, l16 = lane & 15;
    const int wm = (wave >> 1) * 64, wn = (wave & 1) * 64;
    const int row0 = blockIdx.x * 128, col0 = blockIdx.y * 128;

    floatx4 acc[4][4] = {};

    const int srow = t >> 3;          // 0..31
    const int sunit = (t & 7) * 8;    // bf16 col offset 0..56
    const u16* ga = A + (size_t)(row0 + srow) * K + sunit;
    const u16* gb = Bt + (size_t)(col0 + srow) * K + sunit;

    for (int k0 = 0; k0 < K; k0 += 64) {
        uint4 av[4], bv[4];
#pragma unroll
        for (int p = 0; p < 4; ++p) {
            av[p] = *(const uint4*)(ga + (size_t)(32 * p) * K + k0);
            bv[p] = *(const uint4*)(gb + (size_t)(32 * p) * K + k0);
        }
        __syncthreads();
#pragma unroll
        for (int p = 0; p < 4; ++p) {
            *(uint4*)(As + (srow + 32 * p) * 72 + sunit) = av[p];
            *(uint4*)(Bs + (srow + 32 * p) * 72 + sunit) = bv[p];
        }
        __syncthreads();
#pragma unroll
        for (int c = 0; c < 2; ++c) {
            short8 af[4], bfr[4];
#pragma unroll
            for (int mi = 0; mi < 4; ++mi)
                af[mi] = *(const short8*)(As + (wm + mi * 16 + l16) * 72 + 32 * c + quad * 8);
#pragma unroll
            for (int ni = 0; ni < 4; ++ni)
                bfr[ni] = *(const short8*)(Bs + (wn + ni * 16 + l16) * 72 + 32 * c + quad * 8);
#pragma unroll
            for (int mi = 0; mi < 4; ++mi)
#pragma unroll
                for (int ni = 0; ni < 4; ++ni)
                    acc[mi][ni] = __builtin_amdgcn_mfma_f32_16x16x32_bf16(
                        af[mi], bfr[ni], acc[mi][ni], 0, 0, 0);
        }
    }
    // epilogue: D row=(quad*4+r), col=l16 per 16x16 tile
    if (store_bf16) {
        u16* Cp = (u16*)C;
#pragma unroll
        for (int mi = 0; mi < 4; ++mi) {
            int row = row0 + wm + mi * 16 + quad * 4;
#pragma unroll
            for (int ni = 0; ni < 4; ++ni) {
                int col = col0 + wn + ni * 16 + l16;
                float bval = bias[col];
#pragma unroll
                for (int r = 0; r < 4; ++r)
                    Cp[(size_t)(row + r) * N + col] = f2bu(acc[mi][ni][r] + bval);
            }
        }
    } else {
        float* Cp = (float*)C;
#pragma unroll
        for (int mi = 0; mi < 4; ++mi) {
            int row = row0 + wm + mi * 16 + quad * 4;
#pragma unroll
            for (int ni = 0; ni < 4; ++ni) {
                int col = col0 + wn + ni * 16 + l16;
                float bval = bias[col];
#pragma unroll
                for (int r = 0; r < 4; ++r)
                    Cp[(size_t)(row + r) * N + col] = acc[mi][ni][r] + bval;
            }
        }
    }
}

// ==========  RoPE (head 0 only) + scatter to Q/K [b][h][n][d], V^T [b][h][d][n]  ==========
__global__ __launch_bounds__(256) void k_rope_scatter(const u16* __restrict__ qkv,
                                                      const float* __restrict__ freqs,
                                                      u16* __restrict__ Qg,
                                                      u16* __restrict__ Kg,
                                                      u16* __restrict__ Vtg) {
    __shared__ u16 vt[64 * 72];
    const int t = threadIdx.x;
    const int n0 = blockIdx.x * 64, h = blockIdx.y, b = blockIdx.z;
    const int nl = t >> 2;            // 0..63
    const int d0 = (t & 3) * 16;
    const int n = n0 + nl;
    const size_t rowbase = ((size_t)(b * N_ + n)) * 3072 + h * HD_ + d0;
    const size_t bh = (size_t)(b * H_ + h);

#pragma unroll
    for (int sel = 0; sel < 2; ++sel) {   // 0: Q, 1: K
        const u16* src = qkv + rowbase + sel * INNER_;
        float vals[16];
#pragma unroll
        for (int i = 0; i < 16; ++i) vals[i] = bu2f(src[i]);
        if (h == 0) {
            const float* f = freqs + n * HD_ + d0;
#pragma unroll
            for (int i = 0; i < 8; ++i) {
                float fe = f[2 * i], fo = f[2 * i + 1];
                float ve = vals[2 * i], vo = vals[2 * i + 1];
                vals[2 * i]     = ve * __cosf(fe) - vo * __sinf(fe);
                vals[2 * i + 1] = vo * __cosf(fo) + ve * __sinf(fo);
            }
        }
        u16 outv[16];
#pragma unroll
        for (int i = 0; i < 16; ++i) outv[i] = f2bu(vals[i]);
        u16* dst = (sel == 0 ? Qg : Kg) + (bh * N_ + n) * HD_ + d0;
        *(uint4*)dst = *(uint4*)outv;
        *(uint4*)(dst + 8) = *((uint4*)outv + 1);
    }
    // V: transpose 64x64 tile via LDS
    {
        const u16* src = qkv + rowbase + 2 * INNER_;
#pragma unroll
        for (int i = 0; i < 16; ++i) vt[(d0 + i) * 72 + nl] = src[i];
        __syncthreads();
        const int d = t >> 2;
        const int c0 = (t & 3) * 16;
        u16* dst = Vtg + (bh * HD_ + d) * N_ + n0 + c0;
        u16 tmp[16];
#pragma unroll
        for (int i = 0; i < 16; ++i) tmp[i] = vt[d * 72 + c0 + i];
        *(uint4*)dst = *(uint4*)tmp;
        *(uint4*)(dst + 8) = *((uint4*)tmp + 1);
    }
}

// ==========  sliding-window flash attention; block = (64 q-rows, h, b)  ==========
__global__ __launch_bounds__(256) void k_attn(const u16* __restrict__ Qg,
                                              const u16* __restrict__ Kg,
                                              const u16* __restrict__ Vtg,
                                              u16* __restrict__ Og) {
    __shared__ u16 Qs[64 * 72];
    __shared__ u16 Ks[64 * 72];
    __shared__ u16 Vs[64 * 72];
    __shared__ u16 Ps[4 * 16 * 72];
    const int t = threadIdx.x;
    const int wave = t >> 6, lane = t & 63;
    const int quad = lane >> 4, l16 = lane & 15;
    const int q0 = blockIdx.x * 64;
    const int h = blockIdx.y, b = blockIdx.z;
    const size_t bh = (size_t)(b * H_ + h);

    // stage Q tile (64 x 64)
    {
        const int srow = t >> 2;
        const int su = (t & 3) * 16;
        const u16* qp = Qg + (bh * N_ + q0 + srow) * HD_ + su;
        uint4 v0 = *(const uint4*)(qp);
        uint4 v1 = *(const uint4*)(qp + 8);
        *(uint4*)(Qs + srow * 72 + su) = v0;
        *(uint4*)(Qs + srow * 72 + su + 8) = v1;
    }
    __syncthreads();

    floatx4 oacc[4] = {};
    float mrow[4], lrow[4];
#pragma unroll
    for (int r = 0; r < 4; ++r) { mrow[r] = -1e30f; lrow[r] = 0.f; }
    const int qrow_base = q0 + wave * 16 + quad * 4;

    for (int tt = 0; tt < 5; ++tt) {
        const int j0 = q0 - 128 + tt * 64;
        if (j0 < 0 || j0 >= N_) continue;   // uniform across block
        __syncthreads();                    // prev tile's reads done
        {
            const int srow = t >> 2;
            const int su = (t & 3) * 16;
            const u16* kp = Kg + (bh * N_ + j0 + srow) * HD_ + su;
            uint4 k0v = *(const uint4*)(kp);
            uint4 k1v = *(const uint4*)(kp + 8);
            const u16* vp = Vtg + (bh * HD_ + srow) * N_ + j0 + su;
            uint4 v0v = *(const uint4*)(vp);
            uint4 v1v = *(const uint4*)(vp + 8);
            *(uint4*)(Ks + srow * 72 + su) = k0v;
            *(uint4*)(Ks + srow * 72 + su + 8) = k1v;
            *(uint4*)(Vs + srow * 72 + su) = v0v;
            *(uint4*)(Vs + srow * 72 + su + 8) = v1v;
        }
        __syncthreads();

        // S = Q K^T (16q x 64j per wave)
        floatx4 s[4] = {};
        short8 aq0 = *(const short8*)(Qs + (wave * 16 + l16) * 72 + quad * 8);
        short8 aq1 = *(const short8*)(Qs + (wave * 16 + l16) * 72 + 32 + quad * 8);
#pragma unroll
        for (int ni = 0; ni < 4; ++ni) {
            short8 bk0 = *(const short8*)(Ks + (ni * 16 + l16) * 72 + quad * 8);
            short8 bk1 = *(const short8*)(Ks + (ni * 16 + l16) * 72 + 32 + quad * 8);
            s[ni] = __builtin_amdgcn_mfma_f32_16x16x32_bf16(aq0, bk0, s[ni], 0, 0, 0);
            s[ni] = __builtin_amdgcn_mfma_f32_16x16x32_bf16(aq1, bk1, s[ni], 0, 0, 0);
        }
        // scale + window mask
#pragma unroll
        for (int ni = 0; ni < 4; ++ni)
#pragma unroll
            for (int r = 0; r < 4; ++r) {
                int dj = (j0 + ni * 16 + l16) - (qrow_base + r);
                bool valid = (dj >= -HALF_W) && (dj <= HALF_W);
                s[ni][r] = valid ? s[ni][r] * 0.125f : -1e30f;
            }
        // online softmax
        float newm[4];
#pragma unroll
        for (int r = 0; r < 4; ++r) {
            float v = fmaxf(fmaxf(s[0][r], s[1][r]), fmaxf(s[2][r], s[3][r]));
            v = fmaxf(v, __shfl_xor(v, 1)); v = fmaxf(v, __shfl_xor(v, 2));
            v = fmaxf(v, __shfl_xor(v, 4)); v = fmaxf(v, __shfl_xor(v, 8));
            newm[r] = fmaxf(mrow[r], v);
        }
#pragma unroll
        for (int ni = 0; ni < 4; ++ni)
#pragma unroll
            for (int r = 0; r < 4; ++r)
                s[ni][r] = __expf(s[ni][r] - newm[r]);
#pragma unroll
        for (int r = 0; r < 4; ++r) {
            float v = s[0][r] + s[1][r] + s[2][r] + s[3][r];
            v += __shfl_xor(v, 1); v += __shfl_xor(v, 2);
            v += __shfl_xor(v, 4); v += __shfl_xor(v, 8);
            float alpha = __expf(mrow[r] - newm[r]);
            lrow[r] = lrow[r] * alpha + v;
            mrow[r] = newm[r];
#pragma unroll
            for (int ni = 0; ni < 4; ++ni) oacc[ni][r] *= alpha;
        }
        // P -> LDS (C-layout -> A-layout round trip), wave-private section
        u16* pw = Ps + wave * 16 * 72;
#pragma unroll
        for (int ni = 0; ni < 4; ++ni)
#pragma unroll
            for (int r = 0; r < 4; ++r)
                pw[(quad * 4 + r) * 72 + ni * 16 + l16] = f2bu(s[ni][r]);
        __syncthreads();
        // O += P V
#pragma unroll
        for (int c = 0; c < 2; ++c) {
            short8 pf = *(const short8*)(pw + l16 * 72 + 32 * c + quad * 8);
#pragma unroll
            for (int ni = 0; ni < 4; ++ni) {
                short8 vf = *(const short8*)(Vs + (ni * 16 + l16) * 72 + 32 * c + quad * 8);
                oacc[ni] = __builtin_amdgcn_mfma_f32_16x16x32_bf16(pf, vf, oacc[ni], 0, 0, 0);
            }
        }
    }
    // epilogue: Og[b][n][h*64+d] bf16
    u16* outp = Og + ((size_t)b * N_ + q0 + wave * 16 + quad * 4) * INNER_ + h * HD_;
#pragma unroll
    for (int ni = 0; ni < 4; ++ni)
#pragma unroll
        for (int r = 0; r < 4; ++r) {
            float v = oacc[ni][r] / lrow[r];
            outp[(size_t)r * INNER_ + ni * 16 + l16] = f2bu(v);
        }
}

// =====================  host side  =====================
extern "C" void kernel_launch(void* const* d_in, const int* in_sizes, int n_in,
                              void* d_out, int out_size, void* d_ws, size_t ws_size,
                              hipStream_t stream) {
    const float* x     = (const float*)d_in[0];
    const float* freqs = (const float*)d_in[2];
    const float* Wq    = (const float*)d_in[3];
    const float* bq    = (const float*)d_in[4];
    const float* Wk    = (const float*)d_in[5];
    const float* bk    = (const float*)d_in[6];
    const float* Wv    = (const float*)d_in[7];
    const float* bv    = (const float*)d_in[8];
    const float* Wo    = (const float*)d_in[9];
    const float* bo    = (const float*)d_in[10];
    // mask (d_in[1]) is all-ones; window_size (d_in[11]) == 256 per problem spec.

    char* w = (char*)d_ws;
    u16* xb       = (u16*)w;  w += (size_t)4096 * 1024 * 2;        // 8 MB
    u16* wqkvt    = (u16*)w;  w += (size_t)3072 * 1024 * 2;        // 6 MB
    u16* wot      = (u16*)w;  w += (size_t)1024 * 1024 * 2;        // 2 MB
    float* bias_qkv = (float*)w; w += 3072 * 4;
    float* bias_o   = (float*)w; w += 1024 * 4;
    u16* qkv      = (u16*)w;  w += (size_t)4096 * 3072 * 2;        // 24 MB
    u16* Qb       = (u16*)w;  w += (size_t)B_ * H_ * N_ * HD_ * 2; // 8 MB
    u16* Kb       = (u16*)w;  w += (size_t)B_ * H_ * N_ * HD_ * 2; // 8 MB
    u16* Vtb      = (u16*)w;  w += (size_t)B_ * H_ * N_ * HD_ * 2; // 8 MB
    u16* attn     = (u16*)w;  w += (size_t)4096 * 1024 * 2;        // 8 MB

    k_convert_x<<<4096, 256, 0, stream>>>(x, xb, 4096 * 1024);
    k_transpose_w<<<dim3(16, 16), 256, 0, stream>>>(Wq, wqkvt);
    k_transpose_w<<<dim3(16, 16), 256, 0, stream>>>(Wk, wqkvt + (size_t)1024 * 1024);
    k_transpose_w<<<dim3(16, 16), 256, 0, stream>>>(Wv, wqkvt + (size_t)2048 * 1024);
    k_transpose_w<<<dim3(16, 16), 256, 0, stream>>>(Wo, wot);
    k_pack_bias<<<4, 256, 0, stream>>>(bq, bk, bv, bo, bias_qkv, bias_o);

    // QKV GEMM: [4096 x 1024] x [3072 x 1024]^T -> bf16 qkv
    k_gemm_bt<<<dim3(32, 24), 256, 0, stream>>>(xb, wqkvt, bias_qkv, qkv,
                                                4096, 3072, 1024, 1);
    k_rope_scatter<<<dim3(32, 16, 2), 256, 0, stream>>>(qkv, freqs, Qb, Kb, Vtb);
    k_attn<<<dim3(32, 16, 2), 256, 0, stream>>>(Qb, Kb, Vtb, attn);
    // out-proj: [4096 x 1024] x [1024 x 1024]^T -> fp32 d_out
    k_gemm_bt<<<dim3(32, 8), 256, 0, stream>>>(attn, wot, bias_o, (float*)d_out,
                                               4096, 1024, 1024, 0);
}

// Round 2
// 213.452 us; speedup vs baseline: 1.4575x; 1.4575x over previous
//
#include <hip/hip_runtime.h>
#include <hip/hip_bf16.h>
#include <stdint.h>

#define B_ 2
#define N_ 2048
#define D_ 1024
#define H_ 16
#define HD_ 64
#define INNER_ 1024
#define HALF_W 128

typedef unsigned short u16;
typedef __attribute__((ext_vector_type(8))) short short8;
typedef __attribute__((ext_vector_type(4))) float floatx4;

// ---- bf16 <-> f32 bit helpers ----
__device__ inline u16 f2bu(float x) {
    union { float f; uint32_t u; } c; c.f = x;
    uint32_t u = c.u;
    uint32_t r = (u + 0x7FFFu + ((u >> 16) & 1u)) >> 16;
    return (u16)r;
}
__device__ inline float bu2f(u16 v) {
    union { float f; uint32_t u; } c; c.u = ((uint32_t)v) << 16;
    return c.f;
}

// ---- async global->LDS, 16B per lane (dest = wave-uniform base + lane*16) ----
__device__ inline void glds16(const u16* g, u16* l) {
    __builtin_amdgcn_global_load_lds(
        (const __attribute__((address_space(1))) uint32_t*)g,
        (__attribute__((address_space(3))) uint32_t*)l, 16, 0, 0);
}

// =====================  convert x: fp32 -> bf16  =====================
__global__ __launch_bounds__(256) void k_convert_x(const float* __restrict__ x,
                                                   u16* __restrict__ xb, int n) {
    int i = (blockIdx.x * 256 + threadIdx.x) * 4;
    if (i < n) {
        float4 v = *(const float4*)(x + i);
        uint32_t p0 = (uint32_t)f2bu(v.x) | ((uint32_t)f2bu(v.y) << 16);
        uint32_t p1 = (uint32_t)f2bu(v.z) | ((uint32_t)f2bu(v.w) << 16);
        uint2 o; o.x = p0; o.y = p1;
        *(uint2*)(xb + i) = o;
    }
}

// ============  transpose+convert W: fp32 [1024][1024] -> bf16 [n][k]  ============
__global__ __launch_bounds__(256) void k_transpose_w(const float* __restrict__ src,
                                                     u16* __restrict__ dst) {
    __shared__ float ts[64][65];
    const int kb = blockIdx.x, nb = blockIdx.y;
    const int t = threadIdx.x;
    const int row = t >> 2;
    const int c4 = (t & 3) * 16;
    const float* s = src + (size_t)(kb * 64 + row) * 1024 + nb * 64 + c4;
#pragma unroll
    for (int i = 0; i < 16; i += 4) {
        float4 v = *(const float4*)(s + i);
        ts[row][c4 + i] = v.x; ts[row][c4 + i + 1] = v.y;
        ts[row][c4 + i + 2] = v.z; ts[row][c4 + i + 3] = v.w;
    }
    __syncthreads();
    const int n = row;
    u16* d = dst + (size_t)(nb * 64 + n) * 1024 + kb * 64 + c4;
    u16 tmp[16];
#pragma unroll
    for (int i = 0; i < 16; ++i) tmp[i] = f2bu(ts[c4 + i][n]);
    *(uint4*)(d) = *(uint4*)tmp;
    *(uint4*)(d + 8) = *((uint4*)tmp + 1);
}

// =====================  pack biases  =====================
__global__ void k_pack_bias(const float* bq, const float* bk, const float* bv,
                            const float* bo, float* bias_qkv, float* bias_o) {
    int i = blockIdx.x * 256 + threadIdx.x;
    if (i < 1024) {
        bias_qkv[i] = bq[i];
        bias_qkv[1024 + i] = bk[i];
        bias_qkv[2048 + i] = bv[i];
        bias_o[i] = bo[i];
    }
}

// ============  bf16 MFMA GEMM (m97 structure): C = A[M][K] * Bt[N][K]^T + bias  ============
// block 256 = 4 waves, tile 128x128, BK=64; wave -> 64x64 (4x4 mfma_16x16x32 accs)
// LDS unpadded [row][64]; staging via global_load_lds width=16; coalesced LDS-staged epilogue.
__global__ __launch_bounds__(256) void k_gemm_bt(const u16* __restrict__ A,
                                                 const u16* __restrict__ Bt,
                                                 const float* __restrict__ bias,
                                                 void* __restrict__ C,
                                                 int M, int N, int K, int store_bf16) {
    __shared__ u16 smem[2 * 128 * 64];           // As | Bs ; reused as C staging
    u16* As = smem;
    u16* Bs = smem + 128 * 64;
    const int t = threadIdx.x;
    const int wave = t >> 6, lane = t & 63;
    const int quad = lane >> 4, l16 = lane & 15;
    const int wm = (wave >> 1) * 64, wn = (wave & 1) * 64;
    const int row0 = blockIdx.x * 128, col0 = blockIdx.y * 128;

    floatx4 acc[4][4] = {};

    // staging map: thread t -> LDS u16 offset t*8 (+ rr*2048); global row t/8 (+ rr*32), col8 t%8
    const int srow = t >> 3;          // 0..31
    const int scol = (t & 7) * 8;     // 0..56
    const u16* gA = A + (size_t)(row0 + srow) * K + scol;
    const u16* gB = Bt + (size_t)(col0 + srow) * K + scol;
    u16* lA = As + t * 8;
    u16* lB = Bs + t * 8;

    for (int k0 = 0; k0 < K; k0 += 64) {
        __syncthreads();              // previous tile's ds_reads done
#pragma unroll
        for (int rr = 0; rr < 4; ++rr) {
            glds16(gA + (size_t)(rr * 32) * K + k0, lA + rr * 2048);
            glds16(gB + (size_t)(rr * 32) * K + k0, lB + rr * 2048);
        }
        __syncthreads();              // drains vmcnt before compute
#pragma unroll
        for (int c = 0; c < 2; ++c) {
            short8 af[4], bfr[4];
#pragma unroll
            for (int mi = 0; mi < 4; ++mi)
                af[mi] = *(const short8*)(As + (wm + mi * 16 + l16) * 64 + 32 * c + quad * 8);
#pragma unroll
            for (int ni = 0; ni < 4; ++ni)
                bfr[ni] = *(const short8*)(Bs + (wn + ni * 16 + l16) * 64 + 32 * c + quad * 8);
#pragma unroll
            for (int mi = 0; mi < 4; ++mi)
#pragma unroll
                for (int ni = 0; ni < 4; ++ni)
                    acc[mi][ni] = __builtin_amdgcn_mfma_f32_16x16x32_bf16(
                        af[mi], bfr[ni], acc[mi][ni], 0, 0, 0);
        }
    }

    // bias per lane's 4 columns
    float bv4[4];
#pragma unroll
    for (int ni = 0; ni < 4; ++ni) bv4[ni] = bias[col0 + wn + ni * 16 + l16];

    __syncthreads();                  // all ds_reads done before reusing smem

    if (store_bf16) {
        // stage full 128x128 bf16 tile in smem (32 KB), then 16B/lane coalesced stores
        u16* Cs = smem;
#pragma unroll
        for (int mi = 0; mi < 4; ++mi)
#pragma unroll
            for (int ni = 0; ni < 4; ++ni)
#pragma unroll
                for (int r = 0; r < 4; ++r)
                    Cs[(wm + mi * 16 + quad * 4 + r) * 128 + wn + ni * 16 + l16] =
                        f2bu(acc[mi][ni][r] + bv4[ni]);
        __syncthreads();
        u16* Cp = (u16*)C;
        const int orow = t >> 4;          // 0..15
        const int oc = (t & 15) * 8;      // 0..120
#pragma unroll
        for (int rr = 0; rr < 8; ++rr) {
            int row = rr * 16 + orow;
            *(uint4*)(Cp + (size_t)(row0 + row) * N + col0 + oc) =
                *(const uint4*)(Cs + row * 128 + oc);
        }
    } else {
        // fp32: stage 64 rows at a time (32 KB), two halves
        float* Cf = (float*)smem;
        float* Cp = (float*)C;
#pragma unroll
        for (int half = 0; half < 2; ++half) {
            if ((wave >> 1) == half) {
#pragma unroll
                for (int mi = 0; mi < 4; ++mi)
#pragma unroll
                    for (int ni = 0; ni < 4; ++ni)
#pragma unroll
                        for (int r = 0; r < 4; ++r)
                            Cf[(mi * 16 + quad * 4 + r) * 128 + wn + ni * 16 + l16] =
                                acc[mi][ni][r] + bv4[ni];
            }
            __syncthreads();
            const int orow = t >> 5;       // 0..7
            const int oc = (t & 31) * 4;   // 0..124
#pragma unroll
            for (int rr = 0; rr < 8; ++rr) {
                int row = rr * 8 + orow;
                *(float4*)(Cp + (size_t)(row0 + half * 64 + row) * N + col0 + oc) =
                    *(const float4*)(Cf + row * 128 + oc);
            }
            __syncthreads();
        }
    }
}

// ==========  RoPE (head 0 only) + scatter to Q/K [b][h][n][d], V^T [b][h][d][n]  ==========
__global__ __launch_bounds__(256) void k_rope_scatter(const u16* __restrict__ qkv,
                                                      const float* __restrict__ freqs,
                                                      u16* __restrict__ Qg,
                                                      u16* __restrict__ Kg,
                                                      u16* __restrict__ Vtg) {
    __shared__ u16 vt[64 * 72];
    const int t = threadIdx.x;
    const int n0 = blockIdx.x * 64, h = blockIdx.y, b = blockIdx.z;
    const int nl = t >> 2;
    const int d0 = (t & 3) * 16;
    const int n = n0 + nl;
    const size_t rowbase = ((size_t)(b * N_ + n)) * 3072 + h * HD_ + d0;
    const size_t bh = (size_t)(b * H_ + h);

#pragma unroll
    for (int sel = 0; sel < 2; ++sel) {
        const u16* src = qkv + rowbase + sel * INNER_;
        float vals[16];
#pragma unroll
        for (int i = 0; i < 16; ++i) vals[i] = bu2f(src[i]);
        if (h == 0) {
            const float* f = freqs + n * HD_ + d0;
#pragma unroll
            for (int i = 0; i < 8; ++i) {
                float fe = f[2 * i], fo = f[2 * i + 1];
                float ve = vals[2 * i], vo = vals[2 * i + 1];
                vals[2 * i]     = ve * __cosf(fe) - vo * __sinf(fe);
                vals[2 * i + 1] = vo * __cosf(fo) + ve * __sinf(fo);
            }
        }
        u16 outv[16];
#pragma unroll
        for (int i = 0; i < 16; ++i) outv[i] = f2bu(vals[i]);
        u16* dst = (sel == 0 ? Qg : Kg) + (bh * N_ + n) * HD_ + d0;
        *(uint4*)dst = *(uint4*)outv;
        *(uint4*)(dst + 8) = *((uint4*)outv + 1);
    }
    {
        const u16* src = qkv + rowbase + 2 * INNER_;
#pragma unroll
        for (int i = 0; i < 16; ++i) vt[(d0 + i) * 72 + nl] = src[i];
        __syncthreads();
        const int d = t >> 2;
        const int c0 = (t & 3) * 16;
        u16* dst = Vtg + (bh * HD_ + d) * N_ + n0 + c0;
        u16 tmp[16];
#pragma unroll
        for (int i = 0; i < 16; ++i) tmp[i] = vt[d * 72 + c0 + i];
        *(uint4*)dst = *(uint4*)tmp;
        *(uint4*)(dst + 8) = *((uint4*)tmp + 1);
    }
}

// ==========  sliding-window flash attention; block = (64 q-rows, h, b)  ==========
__global__ __launch_bounds__(256) void k_attn(const u16* __restrict__ Qg,
                                              const u16* __restrict__ Kg,
                                              const u16* __restrict__ Vtg,
                                              u16* __restrict__ Og) {
    __shared__ u16 Qs[64 * 72];
    __shared__ u16 Ks[64 * 72];
    __shared__ u16 Vs[64 * 72];
    __shared__ u16 Ps[4 * 16 * 72];
    const int t = threadIdx.x;
    const int wave = t >> 6, lane = t & 63;
    const int quad = lane >> 4, l16 = lane & 15;
    const int q0 = blockIdx.x * 64;
    const int h = blockIdx.y, b = blockIdx.z;
    const size_t bh = (size_t)(b * H_ + h);

    {
        const int srow = t >> 2;
        const int su = (t & 3) * 16;
        const u16* qp = Qg + (bh * N_ + q0 + srow) * HD_ + su;
        uint4 v0 = *(const uint4*)(qp);
        uint4 v1 = *(const uint4*)(qp + 8);
        *(uint4*)(Qs + srow * 72 + su) = v0;
        *(uint4*)(Qs + srow * 72 + su + 8) = v1;
    }
    __syncthreads();

    floatx4 oacc[4] = {};
    float mrow[4], lrow[4];
#pragma unroll
    for (int r = 0; r < 4; ++r) { mrow[r] = -1e30f; lrow[r] = 0.f; }
    const int qrow_base = q0 + wave * 16 + quad * 4;

    for (int tt = 0; tt < 5; ++tt) {
        const int j0 = q0 - 128 + tt * 64;
        if (j0 < 0 || j0 >= N_) continue;
        __syncthreads();
        {
            const int srow = t >> 2;
            const int su = (t & 3) * 16;
            const u16* kp = Kg + (bh * N_ + j0 + srow) * HD_ + su;
            uint4 k0v = *(const uint4*)(kp);
            uint4 k1v = *(const uint4*)(kp + 8);
            const u16* vp = Vtg + (bh * HD_ + srow) * N_ + j0 + su;
            uint4 v0v = *(const uint4*)(vp);
            uint4 v1v = *(const uint4*)(vp + 8);
            *(uint4*)(Ks + srow * 72 + su) = k0v;
            *(uint4*)(Ks + srow * 72 + su + 8) = k1v;
            *(uint4*)(Vs + srow * 72 + su) = v0v;
            *(uint4*)(Vs + srow * 72 + su + 8) = v1v;
        }
        __syncthreads();

        floatx4 s[4] = {};
        short8 aq0 = *(const short8*)(Qs + (wave * 16 + l16) * 72 + quad * 8);
        short8 aq1 = *(const short8*)(Qs + (wave * 16 + l16) * 72 + 32 + quad * 8);
#pragma unroll
        for (int ni = 0; ni < 4; ++ni) {
            short8 bk0 = *(const short8*)(Ks + (ni * 16 + l16) * 72 + quad * 8);
            short8 bk1 = *(const short8*)(Ks + (ni * 16 + l16) * 72 + 32 + quad * 8);
            s[ni] = __builtin_amdgcn_mfma_f32_16x16x32_bf16(aq0, bk0, s[ni], 0, 0, 0);
            s[ni] = __builtin_amdgcn_mfma_f32_16x16x32_bf16(aq1, bk1, s[ni], 0, 0, 0);
        }
#pragma unroll
        for (int ni = 0; ni < 4; ++ni)
#pragma unroll
            for (int r = 0; r < 4; ++r) {
                int dj = (j0 + ni * 16 + l16) - (qrow_base + r);
                bool valid = (dj >= -HALF_W) && (dj <= HALF_W);
                s[ni][r] = valid ? s[ni][r] * 0.125f : -1e30f;
            }
        float newm[4];
#pragma unroll
        for (int r = 0; r < 4; ++r) {
            float v = fmaxf(fmaxf(s[0][r], s[1][r]), fmaxf(s[2][r], s[3][r]));
            v = fmaxf(v, __shfl_xor(v, 1)); v = fmaxf(v, __shfl_xor(v, 2));
            v = fmaxf(v, __shfl_xor(v, 4)); v = fmaxf(v, __shfl_xor(v, 8));
            newm[r] = fmaxf(mrow[r], v);
        }
#pragma unroll
        for (int ni = 0; ni < 4; ++ni)
#pragma unroll
            for (int r = 0; r < 4; ++r)
                s[ni][r] = __expf(s[ni][r] - newm[r]);
#pragma unroll
        for (int r = 0; r < 4; ++r) {
            float v = s[0][r] + s[1][r] + s[2][r] + s[3][r];
            v += __shfl_xor(v, 1); v += __shfl_xor(v, 2);
            v += __shfl_xor(v, 4); v += __shfl_xor(v, 8);
            float alpha = __expf(mrow[r] - newm[r]);
            lrow[r] = lrow[r] * alpha + v;
            mrow[r] = newm[r];
#pragma unroll
            for (int ni = 0; ni < 4; ++ni) oacc[ni][r] *= alpha;
        }
        u16* pw = Ps + wave * 16 * 72;
#pragma unroll
        for (int ni = 0; ni < 4; ++ni)
#pragma unroll
            for (int r = 0; r < 4; ++r)
                pw[(quad * 4 + r) * 72 + ni * 16 + l16] = f2bu(s[ni][r]);
        __syncthreads();
#pragma unroll
        for (int c = 0; c < 2; ++c) {
            short8 pf = *(const short8*)(pw + l16 * 72 + 32 * c + quad * 8);
#pragma unroll
            for (int ni = 0; ni < 4; ++ni) {
                short8 vf = *(const short8*)(Vs + (ni * 16 + l16) * 72 + 32 * c + quad * 8);
                oacc[ni] = __builtin_amdgcn_mfma_f32_16x16x32_bf16(pf, vf, oacc[ni], 0, 0, 0);
            }
        }
    }
    u16* outp = Og + ((size_t)b * N_ + q0 + wave * 16 + quad * 4) * INNER_ + h * HD_;
#pragma unroll
    for (int ni = 0; ni < 4; ++ni)
#pragma unroll
        for (int r = 0; r < 4; ++r) {
            float v = oacc[ni][r] / lrow[r];
            outp[(size_t)r * INNER_ + ni * 16 + l16] = f2bu(v);
        }
}

// =====================  host side  =====================
extern "C" void kernel_launch(void* const* d_in, const int* in_sizes, int n_in,
                              void* d_out, int out_size, void* d_ws, size_t ws_size,
                              hipStream_t stream) {
    const float* x     = (const float*)d_in[0];
    const float* freqs = (const float*)d_in[2];
    const float* Wq    = (const float*)d_in[3];
    const float* bq    = (const float*)d_in[4];
    const float* Wk    = (const float*)d_in[5];
    const float* bk    = (const float*)d_in[6];
    const float* Wv    = (const float*)d_in[7];
    const float* bv    = (const float*)d_in[8];
    const float* Wo    = (const float*)d_in[9];
    const float* bo    = (const float*)d_in[10];

    char* w = (char*)d_ws;
    u16* xb       = (u16*)w;  w += (size_t)4096 * 1024 * 2;
    u16* wqkvt    = (u16*)w;  w += (size_t)3072 * 1024 * 2;
    u16* wot      = (u16*)w;  w += (size_t)1024 * 1024 * 2;
    float* bias_qkv = (float*)w; w += 3072 * 4;
    float* bias_o   = (float*)w; w += 1024 * 4;
    u16* qkv      = (u16*)w;  w += (size_t)4096 * 3072 * 2;
    u16* Qb       = (u16*)w;  w += (size_t)B_ * H_ * N_ * HD_ * 2;
    u16* Kb       = (u16*)w;  w += (size_t)B_ * H_ * N_ * HD_ * 2;
    u16* Vtb      = (u16*)w;  w += (size_t)B_ * H_ * N_ * HD_ * 2;
    u16* attn     = (u16*)w;  w += (size_t)4096 * 1024 * 2;

    k_convert_x<<<4096, 256, 0, stream>>>(x, xb, 4096 * 1024);
    k_transpose_w<<<dim3(16, 16), 256, 0, stream>>>(Wq, wqkvt);
    k_transpose_w<<<dim3(16, 16), 256, 0, stream>>>(Wk, wqkvt + (size_t)1024 * 1024);
    k_transpose_w<<<dim3(16, 16), 256, 0, stream>>>(Wv, wqkvt + (size_t)2048 * 1024);
    k_transpose_w<<<dim3(16, 16), 256, 0, stream>>>(Wo, wot);
    k_pack_bias<<<4, 256, 0, stream>>>(bq, bk, bv, bo, bias_qkv, bias_o);

    k_gemm_bt<<<dim3(32, 24), 256, 0, stream>>>(xb, wqkvt, bias_qkv, qkv,
                                                4096, 3072, 1024, 1);
    k_rope_scatter<<<dim3(32, 16, 2), 256, 0, stream>>>(qkv, freqs, Qb, Kb, Vtb);
    k_attn<<<dim3(32, 16, 2), 256, 0, stream>>>(Qb, Kb, Vtb, attn);
    k_gemm_bt<<<dim3(32, 8), 256, 0, stream>>>(attn, wot, bias_o, (float*)d_out,
                                               4096, 1024, 1024, 0);
}

// Round 3
// 200.271 us; speedup vs baseline: 1.5535x; 1.0658x over previous
//
#include <hip/hip_runtime.h>
#include <hip/hip_bf16.h>
#include <stdint.h>

#define B_ 2
#define N_ 2048
#define D_ 1024
#define H_ 16
#define HD_ 64
#define INNER_ 1024
#define HALF_W 128

typedef unsigned short u16;
typedef __attribute__((ext_vector_type(8))) short short8;
typedef __attribute__((ext_vector_type(4))) float floatx4;

// ---- bf16 <-> f32 bit helpers ----
__device__ inline u16 f2bu(float x) {
    union { float f; uint32_t u; } c; c.f = x;
    uint32_t u = c.u;
    uint32_t r = (u + 0x7FFFu + ((u >> 16) & 1u)) >> 16;
    return (u16)r;
}
__device__ inline float bu2f(u16 v) {
    union { float f; uint32_t u; } c; c.u = ((uint32_t)v) << 16;
    return c.f;
}

// ---- async global->LDS, 16B per lane (dest = wave-uniform base + lane*16) ----
__device__ inline void glds16(const u16* g, u16* l) {
    __builtin_amdgcn_global_load_lds(
        (const __attribute__((address_space(1))) uint32_t*)g,
        (__attribute__((address_space(3))) uint32_t*)l, 16, 0, 0);
}

// =====================  convert x: fp32 -> bf16  =====================
__global__ __launch_bounds__(256) void k_convert_x(const float* __restrict__ x,
                                                   u16* __restrict__ xb, int n) {
    int i = (blockIdx.x * 256 + threadIdx.x) * 4;
    if (i < n) {
        float4 v = *(const float4*)(x + i);
        uint32_t p0 = (uint32_t)f2bu(v.x) | ((uint32_t)f2bu(v.y) << 16);
        uint32_t p1 = (uint32_t)f2bu(v.z) | ((uint32_t)f2bu(v.w) << 16);
        uint2 o; o.x = p0; o.y = p1;
        *(uint2*)(xb + i) = o;
    }
}

// ====  transpose+convert all 4 weights: fp32 [1024][1024] -> bf16 [n][k], z picks W  ====
__global__ __launch_bounds__(256) void k_transpose_w4(const float* __restrict__ Wq,
                                                      const float* __restrict__ Wk,
                                                      const float* __restrict__ Wv,
                                                      const float* __restrict__ Wo,
                                                      u16* __restrict__ wqkvt,
                                                      u16* __restrict__ wot) {
    __shared__ float ts[64][65];
    const int z = blockIdx.z;
    const float* src = (z == 0) ? Wq : (z == 1) ? Wk : (z == 2) ? Wv : Wo;
    u16* dst = (z < 3) ? (wqkvt + (size_t)z * 1024 * 1024) : wot;
    const int kb = blockIdx.x, nb = blockIdx.y;
    const int t = threadIdx.x;
    const int row = t >> 2;
    const int c4 = (t & 3) * 16;
    const float* s = src + (size_t)(kb * 64 + row) * 1024 + nb * 64 + c4;
#pragma unroll
    for (int i = 0; i < 16; i += 4) {
        float4 v = *(const float4*)(s + i);
        ts[row][c4 + i] = v.x; ts[row][c4 + i + 1] = v.y;
        ts[row][c4 + i + 2] = v.z; ts[row][c4 + i + 3] = v.w;
    }
    __syncthreads();
    const int n = row;
    u16* d = dst + (size_t)(nb * 64 + n) * 1024 + kb * 64 + c4;
    u16 tmp[16];
#pragma unroll
    for (int i = 0; i < 16; ++i) tmp[i] = f2bu(ts[c4 + i][n]);
    *(uint4*)(d) = *(uint4*)tmp;
    *(uint4*)(d + 8) = *((uint4*)tmp + 1);
}

// =====================  pack biases  =====================
__global__ void k_pack_bias(const float* bq, const float* bk, const float* bv,
                            const float* bo, float* bias_qkv, float* bias_o) {
    int i = blockIdx.x * 256 + threadIdx.x;
    if (i < 1024) {
        bias_qkv[i] = bq[i];
        bias_qkv[1024 + i] = bk[i];
        bias_qkv[2048 + i] = bv[i];
        bias_o[i] = bo[i];
    }
}

// ============  bf16 MFMA GEMM: C = A[M][K] * Bt[N][K]^T + bias  ============
// block 256 = 4 waves, tile 128x128, BK=64; global_load_lds w/ XOR-swizzled LDS chunks:
// LDS chunk (row, j) holds global chunk (row, j ^ (row&7)); 16B chunks, row stride 64 u16.
// Fragment ds_read_b128 hits 8 distinct 4-bank groups per quad -> 2-way aliasing (free).
__global__ __launch_bounds__(256) void k_gemm_bt(const u16* __restrict__ A,
                                                 const u16* __restrict__ Bt,
                                                 const float* __restrict__ bias,
                                                 void* __restrict__ C,
                                                 int M, int N, int K, int store_bf16) {
    __shared__ u16 smem[2 * 128 * 64];           // As | Bs ; reused as C staging
    u16* As = smem;
    u16* Bs = smem + 128 * 64;
    const int t = threadIdx.x;
    const int wave = t >> 6, lane = t & 63;
    const int quad = lane >> 4, l16 = lane & 15;
    const int wm = (wave >> 1) * 64, wn = (wave & 1) * 64;
    const int row0 = blockIdx.x * 128, col0 = blockIdx.y * 128;

    floatx4 acc[4][4] = {};

    // staging: lane t -> LDS u16 offset t*8 (+ rr*2048); global row t>>3 (+rr*32),
    // global col chunk = (t&7) ^ ((t>>3)&7)  [XOR swizzle; (row+32rr)&7 == row&7]
    const int srow = t >> 3;                       // 0..31
    const int scol = (((t & 7) ^ (srow & 7)) * 8); // swizzled u16 col
    const u16* gA = A + (size_t)(row0 + srow) * K + scol;
    const u16* gB = Bt + (size_t)(col0 + srow) * K + scol;
    u16* lA = As + t * 8;
    u16* lB = Bs + t * 8;

    for (int k0 = 0; k0 < K; k0 += 64) {
        __syncthreads();              // previous tile's ds_reads done
#pragma unroll
        for (int rr = 0; rr < 4; ++rr) {
            glds16(gA + (size_t)(rr * 32) * K + k0, lA + rr * 2048);
            glds16(gB + (size_t)(rr * 32) * K + k0, lB + rr * 2048);
        }
        __syncthreads();              // drains vmcnt before compute
#pragma unroll
        for (int c = 0; c < 2; ++c) {
            short8 af[4], bfr[4];
            const int swz = ((4 * c + quad) ^ (l16 & 7)) * 8;  // swizzled u16 offset
#pragma unroll
            for (int mi = 0; mi < 4; ++mi)
                af[mi] = *(const short8*)(As + (wm + mi * 16 + l16) * 64 + swz);
#pragma unroll
            for (int ni = 0; ni < 4; ++ni)
                bfr[ni] = *(const short8*)(Bs + (wn + ni * 16 + l16) * 64 + swz);
#pragma unroll
            for (int mi = 0; mi < 4; ++mi)
#pragma unroll
                for (int ni = 0; ni < 4; ++ni)
                    acc[mi][ni] = __builtin_amdgcn_mfma_f32_16x16x32_bf16(
                        af[mi], bfr[ni], acc[mi][ni], 0, 0, 0);
        }
    }

    float bv4[4];
#pragma unroll
    for (int ni = 0; ni < 4; ++ni) bv4[ni] = bias[col0 + wn + ni * 16 + l16];

    __syncthreads();                  // all ds_reads done before reusing smem

    if (store_bf16) {
        u16* Cs = smem;
#pragma unroll
        for (int mi = 0; mi < 4; ++mi)
#pragma unroll
            for (int ni = 0; ni < 4; ++ni)
#pragma unroll
                for (int r = 0; r < 4; ++r)
                    Cs[(wm + mi * 16 + quad * 4 + r) * 128 + wn + ni * 16 + l16] =
                        f2bu(acc[mi][ni][r] + bv4[ni]);
        __syncthreads();
        u16* Cp = (u16*)C;
        const int orow = t >> 4;
        const int oc = (t & 15) * 8;
#pragma unroll
        for (int rr = 0; rr < 8; ++rr) {
            int row = rr * 16 + orow;
            *(uint4*)(Cp + (size_t)(row0 + row) * N + col0 + oc) =
                *(const uint4*)(Cs + row * 128 + oc);
        }
    } else {
        float* Cf = (float*)smem;
        float* Cp = (float*)C;
#pragma unroll
        for (int half = 0; half < 2; ++half) {
            if ((wave >> 1) == half) {
#pragma unroll
                for (int mi = 0; mi < 4; ++mi)
#pragma unroll
                    for (int ni = 0; ni < 4; ++ni)
#pragma unroll
                        for (int r = 0; r < 4; ++r)
                            Cf[(mi * 16 + quad * 4 + r) * 128 + wn + ni * 16 + l16] =
                                acc[mi][ni][r] + bv4[ni];
            }
            __syncthreads();
            const int orow = t >> 5;
            const int oc = (t & 31) * 4;
#pragma unroll
            for (int rr = 0; rr < 8; ++rr) {
                int row = rr * 8 + orow;
                *(float4*)(Cp + (size_t)(row0 + half * 64 + row) * N + col0 + oc) =
                    *(const float4*)(Cf + row * 128 + oc);
            }
            __syncthreads();
        }
    }
}

// ==========  RoPE (head 0 only) + scatter to Q/K [b][h][n][d], V^T [b][h][d][n]  ==========
__global__ __launch_bounds__(256) void k_rope_scatter(const u16* __restrict__ qkv,
                                                      const float* __restrict__ freqs,
                                                      u16* __restrict__ Qg,
                                                      u16* __restrict__ Kg,
                                                      u16* __restrict__ Vtg) {
    __shared__ u16 vt[64 * 72];
    const int t = threadIdx.x;
    const int n0 = blockIdx.x * 64, h = blockIdx.y, b = blockIdx.z;
    const int nl = t >> 2;
    const int d0 = (t & 3) * 16;
    const int n = n0 + nl;
    const size_t rowbase = ((size_t)(b * N_ + n)) * 3072 + h * HD_ + d0;
    const size_t bh = (size_t)(b * H_ + h);

#pragma unroll
    for (int sel = 0; sel < 2; ++sel) {
        const u16* src = qkv + rowbase + sel * INNER_;
        float vals[16];
#pragma unroll
        for (int i = 0; i < 16; ++i) vals[i] = bu2f(src[i]);
        if (h == 0) {
            const float* f = freqs + n * HD_ + d0;
#pragma unroll
            for (int i = 0; i < 8; ++i) {
                float fe = f[2 * i], fo = f[2 * i + 1];
                float ve = vals[2 * i], vo = vals[2 * i + 1];
                vals[2 * i]     = ve * __cosf(fe) - vo * __sinf(fe);
                vals[2 * i + 1] = vo * __cosf(fo) + ve * __sinf(fo);
            }
        }
        u16 outv[16];
#pragma unroll
        for (int i = 0; i < 16; ++i) outv[i] = f2bu(vals[i]);
        u16* dst = (sel == 0 ? Qg : Kg) + (bh * N_ + n) * HD_ + d0;
        *(uint4*)dst = *(uint4*)outv;
        *(uint4*)(dst + 8) = *((uint4*)outv + 1);
    }
    {
        const u16* src = qkv + rowbase + 2 * INNER_;
#pragma unroll
        for (int i = 0; i < 16; ++i) vt[(d0 + i) * 72 + nl] = src[i];
        __syncthreads();
        const int d = t >> 2;
        const int c0 = (t & 3) * 16;
        u16* dst = Vtg + (bh * HD_ + d) * N_ + n0 + c0;
        u16 tmp[16];
#pragma unroll
        for (int i = 0; i < 16; ++i) tmp[i] = vt[d * 72 + c0 + i];
        *(uint4*)dst = *(uint4*)tmp;
        *(uint4*)(dst + 8) = *((uint4*)tmp + 1);
    }
}

// ==========  sliding-window flash attention; block = (64 q-rows, h, b)  ==========
__global__ __launch_bounds__(256) void k_attn(const u16* __restrict__ Qg,
                                              const u16* __restrict__ Kg,
                                              const u16* __restrict__ Vtg,
                                              u16* __restrict__ Og) {
    __shared__ u16 Qs[64 * 72];
    __shared__ u16 Ks[64 * 72];
    __shared__ u16 Vs[64 * 72];
    __shared__ u16 Ps[4 * 16 * 72];
    const int t = threadIdx.x;
    const int wave = t >> 6, lane = t & 63;
    const int quad = lane >> 4, l16 = lane & 15;
    const int q0 = blockIdx.x * 64;
    const int h = blockIdx.y, b = blockIdx.z;
    const size_t bh = (size_t)(b * H_ + h);

    {
        const int srow = t >> 2;
        const int su = (t & 3) * 16;
        const u16* qp = Qg + (bh * N_ + q0 + srow) * HD_ + su;
        uint4 v0 = *(const uint4*)(qp);
        uint4 v1 = *(const uint4*)(qp + 8);
        *(uint4*)(Qs + srow * 72 + su) = v0;
        *(uint4*)(Qs + srow * 72 + su + 8) = v1;
    }
    __syncthreads();

    floatx4 oacc[4] = {};
    float mrow[4], lrow[4];
#pragma unroll
    for (int r = 0; r < 4; ++r) { mrow[r] = -1e30f; lrow[r] = 0.f; }
    const int qrow_base = q0 + wave * 16 + quad * 4;

    for (int tt = 0; tt < 5; ++tt) {
        const int j0 = q0 - 128 + tt * 64;
        if (j0 < 0 || j0 >= N_) continue;
        __syncthreads();
        {
            const int srow = t >> 2;
            const int su = (t & 3) * 16;
            const u16* kp = Kg + (bh * N_ + j0 + srow) * HD_ + su;
            uint4 k0v = *(const uint4*)(kp);
            uint4 k1v = *(const uint4*)(kp + 8);
            const u16* vp = Vtg + (bh * HD_ + srow) * N_ + j0 + su;
            uint4 v0v = *(const uint4*)(vp);
            uint4 v1v = *(const uint4*)(vp + 8);
            *(uint4*)(Ks + srow * 72 + su) = k0v;
            *(uint4*)(Ks + srow * 72 + su + 8) = k1v;
            *(uint4*)(Vs + srow * 72 + su) = v0v;
            *(uint4*)(Vs + srow * 72 + su + 8) = v1v;
        }
        __syncthreads();

        floatx4 s[4] = {};
        short8 aq0 = *(const short8*)(Qs + (wave * 16 + l16) * 72 + quad * 8);
        short8 aq1 = *(const short8*)(Qs + (wave * 16 + l16) * 72 + 32 + quad * 8);
#pragma unroll
        for (int ni = 0; ni < 4; ++ni) {
            short8 bk0 = *(const short8*)(Ks + (ni * 16 + l16) * 72 + quad * 8);
            short8 bk1 = *(const short8*)(Ks + (ni * 16 + l16) * 72 + 32 + quad * 8);
            s[ni] = __builtin_amdgcn_mfma_f32_16x16x32_bf16(aq0, bk0, s[ni], 0, 0, 0);
            s[ni] = __builtin_amdgcn_mfma_f32_16x16x32_bf16(aq1, bk1, s[ni], 0, 0, 0);
        }
#pragma unroll
        for (int ni = 0; ni < 4; ++ni)
#pragma unroll
            for (int r = 0; r < 4; ++r) {
                int dj = (j0 + ni * 16 + l16) - (qrow_base + r);
                bool valid = (dj >= -HALF_W) && (dj <= HALF_W);
                s[ni][r] = valid ? s[ni][r] * 0.125f : -1e30f;
            }
        float newm[4];
#pragma unroll
        for (int r = 0; r < 4; ++r) {
            float v = fmaxf(fmaxf(s[0][r], s[1][r]), fmaxf(s[2][r], s[3][r]));
            v = fmaxf(v, __shfl_xor(v, 1)); v = fmaxf(v, __shfl_xor(v, 2));
            v = fmaxf(v, __shfl_xor(v, 4)); v = fmaxf(v, __shfl_xor(v, 8));
            newm[r] = fmaxf(mrow[r], v);
        }
#pragma unroll
        for (int ni = 0; ni < 4; ++ni)
#pragma unroll
            for (int r = 0; r < 4; ++r)
                s[ni][r] = __expf(s[ni][r] - newm[r]);
#pragma unroll
        for (int r = 0; r < 4; ++r) {
            float v = s[0][r] + s[1][r] + s[2][r] + s[3][r];
            v += __shfl_xor(v, 1); v += __shfl_xor(v, 2);
            v += __shfl_xor(v, 4); v += __shfl_xor(v, 8);
            float alpha = __expf(mrow[r] - newm[r]);
            lrow[r] = lrow[r] * alpha + v;
            mrow[r] = newm[r];
#pragma unroll
            for (int ni = 0; ni < 4; ++ni) oacc[ni][r] *= alpha;
        }
        u16* pw = Ps + wave * 16 * 72;
#pragma unroll
        for (int ni = 0; ni < 4; ++ni)
#pragma unroll
            for (int r = 0; r < 4; ++r)
                pw[(quad * 4 + r) * 72 + ni * 16 + l16] = f2bu(s[ni][r]);
        __syncthreads();
#pragma unroll
        for (int c = 0; c < 2; ++c) {
            short8 pf = *(const short8*)(pw + l16 * 72 + 32 * c + quad * 8);
#pragma unroll
            for (int ni = 0; ni < 4; ++ni) {
                short8 vf = *(const short8*)(Vs + (ni * 16 + l16) * 72 + 32 * c + quad * 8);
                oacc[ni] = __builtin_amdgcn_mfma_f32_16x16x32_bf16(pf, vf, oacc[ni], 0, 0, 0);
            }
        }
    }
    u16* outp = Og + ((size_t)b * N_ + q0 + wave * 16 + quad * 4) * INNER_ + h * HD_;
#pragma unroll
    for (int ni = 0; ni < 4; ++ni)
#pragma unroll
        for (int r = 0; r < 4; ++r) {
            float v = oacc[ni][r] / lrow[r];
            outp[(size_t)r * INNER_ + ni * 16 + l16] = f2bu(v);
        }
}

// =====================  host side  =====================
extern "C" void kernel_launch(void* const* d_in, const int* in_sizes, int n_in,
                              void* d_out, int out_size, void* d_ws, size_t ws_size,
                              hipStream_t stream) {
    const float* x     = (const float*)d_in[0];
    const float* freqs = (const float*)d_in[2];
    const float* Wq    = (const float*)d_in[3];
    const float* bq    = (const float*)d_in[4];
    const float* Wk    = (const float*)d_in[5];
    const float* bk    = (const float*)d_in[6];
    const float* Wv    = (const float*)d_in[7];
    const float* bv    = (const float*)d_in[8];
    const float* Wo    = (const float*)d_in[9];
    const float* bo    = (const float*)d_in[10];

    char* w = (char*)d_ws;
    u16* xb       = (u16*)w;  w += (size_t)4096 * 1024 * 2;
    u16* wqkvt    = (u16*)w;  w += (size_t)3072 * 1024 * 2;
    u16* wot      = (u16*)w;  w += (size_t)1024 * 1024 * 2;
    float* bias_qkv = (float*)w; w += 3072 * 4;
    float* bias_o   = (float*)w; w += 1024 * 4;
    u16* qkv      = (u16*)w;  w += (size_t)4096 * 3072 * 2;
    u16* Qb       = (u16*)w;  w += (size_t)B_ * H_ * N_ * HD_ * 2;
    u16* Kb       = (u16*)w;  w += (size_t)B_ * H_ * N_ * HD_ * 2;
    u16* Vtb      = (u16*)w;  w += (size_t)B_ * H_ * N_ * HD_ * 2;
    u16* attn     = (u16*)w;  w += (size_t)4096 * 1024 * 2;

    k_convert_x<<<4096, 256, 0, stream>>>(x, xb, 4096 * 1024);
    k_transpose_w4<<<dim3(16, 16, 4), 256, 0, stream>>>(Wq, Wk, Wv, Wo, wqkvt, wot);
    k_pack_bias<<<4, 256, 0, stream>>>(bq, bk, bv, bo, bias_qkv, bias_o);

    k_gemm_bt<<<dim3(32, 24), 256, 0, stream>>>(xb, wqkvt, bias_qkv, qkv,
                                                4096, 3072, 1024, 1);
    k_rope_scatter<<<dim3(32, 16, 2), 256, 0, stream>>>(qkv, freqs, Qb, Kb, Vtb);
    k_attn<<<dim3(32, 16, 2), 256, 0, stream>>>(Qb, Kb, Vtb, attn);
    k_gemm_bt<<<dim3(32, 8), 256, 0, stream>>>(attn, wot, bias_o, (float*)d_out,
                                               4096, 1024, 1024, 0);
}

// Round 4
// 195.011 us; speedup vs baseline: 1.5954x; 1.0270x over previous
//
#include <hip/hip_runtime.h>
#include <hip/hip_bf16.h>
#include <stdint.h>

#define B_ 2
#define N_ 2048
#define D_ 1024
#define H_ 16
#define HD_ 64
#define INNER_ 1024
#define HALF_W 128

typedef unsigned short u16;
typedef __attribute__((ext_vector_type(8))) short short8;
typedef __attribute__((ext_vector_type(4))) float floatx4;

// ---- bf16 <-> f32 bit helpers ----
__device__ inline u16 f2bu(float x) {
    union { float f; uint32_t u; } c; c.f = x;
    uint32_t u = c.u;
    uint32_t r = (u + 0x7FFFu + ((u >> 16) & 1u)) >> 16;
    return (u16)r;
}
__device__ inline float bu2f(u16 v) {
    union { float f; uint32_t u; } c; c.u = ((uint32_t)v) << 16;
    return c.f;
}

// ---- async global->LDS, 16B per lane (dest = wave-uniform base + lane*16) ----
__device__ inline void glds16(const u16* g, u16* l) {
    __builtin_amdgcn_global_load_lds(
        (const __attribute__((address_space(1))) uint32_t*)g,
        (__attribute__((address_space(3))) uint32_t*)l, 16, 0, 0);
}

// =====================  convert x: fp32 -> bf16  =====================
__global__ __launch_bounds__(256) void k_convert_x(const float* __restrict__ x,
                                                   u16* __restrict__ xb, int n) {
    int i = (blockIdx.x * 256 + threadIdx.x) * 4;
    if (i < n) {
        float4 v = *(const float4*)(x + i);
        uint32_t p0 = (uint32_t)f2bu(v.x) | ((uint32_t)f2bu(v.y) << 16);
        uint32_t p1 = (uint32_t)f2bu(v.z) | ((uint32_t)f2bu(v.w) << 16);
        uint2 o; o.x = p0; o.y = p1;
        *(uint2*)(xb + i) = o;
    }
}

// ====  transpose+convert all 4 weights: fp32 [1024][1024] -> bf16 [n][k], z picks W  ====
__global__ __launch_bounds__(256) void k_transpose_w4(const float* __restrict__ Wq,
                                                      const float* __restrict__ Wk,
                                                      const float* __restrict__ Wv,
                                                      const float* __restrict__ Wo,
                                                      u16* __restrict__ wqkvt,
                                                      u16* __restrict__ wot) {
    __shared__ float ts[64][65];
    const int z = blockIdx.z;
    const float* src = (z == 0) ? Wq : (z == 1) ? Wk : (z == 2) ? Wv : Wo;
    u16* dst = (z < 3) ? (wqkvt + (size_t)z * 1024 * 1024) : wot;
    const int kb = blockIdx.x, nb = blockIdx.y;
    const int t = threadIdx.x;
    const int row = t >> 2;
    const int c4 = (t & 3) * 16;
    const float* s = src + (size_t)(kb * 64 + row) * 1024 + nb * 64 + c4;
#pragma unroll
    for (int i = 0; i < 16; i += 4) {
        float4 v = *(const float4*)(s + i);
        ts[row][c4 + i] = v.x; ts[row][c4 + i + 1] = v.y;
        ts[row][c4 + i + 2] = v.z; ts[row][c4 + i + 3] = v.w;
    }
    __syncthreads();
    const int n = row;
    u16* d = dst + (size_t)(nb * 64 + n) * 1024 + kb * 64 + c4;
    u16 tmp[16];
#pragma unroll
    for (int i = 0; i < 16; ++i) tmp[i] = f2bu(ts[c4 + i][n]);
    *(uint4*)(d) = *(uint4*)tmp;
    *(uint4*)(d + 8) = *((uint4*)tmp + 1);
}

// =====================  pack biases  =====================
__global__ void k_pack_bias(const float* bq, const float* bk, const float* bv,
                            const float* bo, float* bias_qkv, float* bias_o) {
    int i = blockIdx.x * 256 + threadIdx.x;
    if (i < 1024) {
        bias_qkv[i] = bq[i];
        bias_qkv[1024 + i] = bk[i];
        bias_qkv[2048 + i] = bv[i];
        bias_o[i] = bo[i];
    }
}

// ============  QKV GEMM + fused bias/RoPE/scatter epilogue  ============
// C = xb[4096][1024] * wqkvt[3072][1024]^T; tile 128x128, grid (32, 24).
// by 0-7 -> Q, 8-15 -> K (write [bh][n][d], RoPE on head0 strips), 16-23 -> V (write V^T [bh][d][n]).
__global__ __launch_bounds__(256) void k_gemm_qkv(const u16* __restrict__ A,
                                                  const u16* __restrict__ Bt,
                                                  const float* __restrict__ bias,
                                                  const float* __restrict__ freqs,
                                                  u16* __restrict__ Qg,
                                                  u16* __restrict__ Kg,
                                                  u16* __restrict__ Vtg) {
    __shared__ u16 smem[128 * 137];              // K-loop: As|Bs (16384 u16); epilogue staging
    u16* As = smem;
    u16* Bs = smem + 128 * 64;
    const int t = threadIdx.x;
    const int wave = t >> 6, lane = t & 63;
    const int quad = lane >> 4, l16 = lane & 15;
    const int wm = (wave >> 1) * 64, wn = (wave & 1) * 64;
    const int by = blockIdx.y;
    const int row0 = blockIdx.x * 128, col0 = by * 128;

    floatx4 acc[4][4] = {};

    const int srow = t >> 3;                       // 0..31
    const int scol = (((t & 7) ^ (srow & 7)) * 8); // XOR-swizzled col chunk
    const u16* gA = A + (size_t)(row0 + srow) * 1024 + scol;
    const u16* gB = Bt + (size_t)(col0 + srow) * 1024 + scol;
    u16* lA = As + t * 8;
    u16* lB = Bs + t * 8;

    for (int k0 = 0; k0 < 1024; k0 += 64) {
        __syncthreads();
#pragma unroll
        for (int rr = 0; rr < 4; ++rr) {
            glds16(gA + (size_t)(rr * 32) * 1024 + k0, lA + rr * 2048);
            glds16(gB + (size_t)(rr * 32) * 1024 + k0, lB + rr * 2048);
        }
        __syncthreads();
#pragma unroll
        for (int c = 0; c < 2; ++c) {
            short8 af[4], bfr[4];
            const int swz = ((4 * c + quad) ^ (l16 & 7)) * 8;
#pragma unroll
            for (int mi = 0; mi < 4; ++mi)
                af[mi] = *(const short8*)(As + (wm + mi * 16 + l16) * 64 + swz);
#pragma unroll
            for (int ni = 0; ni < 4; ++ni)
                bfr[ni] = *(const short8*)(Bs + (wn + ni * 16 + l16) * 64 + swz);
#pragma unroll
            for (int mi = 0; mi < 4; ++mi)
#pragma unroll
                for (int ni = 0; ni < 4; ++ni)
                    acc[mi][ni] = __builtin_amdgcn_mfma_f32_16x16x32_bf16(
                        af[mi], bfr[ni], acc[mi][ni], 0, 0, 0);
        }
    }

    // bias (ref adds bias before RoPE)
#pragma unroll
    for (int ni = 0; ni < 4; ++ni) {
        float bval = bias[col0 + wn + ni * 16 + l16];
#pragma unroll
        for (int mi = 0; mi < 4; ++mi)
#pragma unroll
            for (int r = 0; r < 4; ++r) acc[mi][ni][r] += bval;
    }

    // RoPE: only head0 of Q (cols 0-63) and head0 of K (cols 1024-1087);
    // wave-uniform branch: by in {0,8} and wn==0.
    if ((by == 0 || by == 8) && wn == 0) {
#pragma unroll
        for (int mi = 0; mi < 4; ++mi)
#pragma unroll
            for (int r = 0; r < 4; ++r) {
                const int n = (row0 + wm + mi * 16 + quad * 4 + r) & (N_ - 1);
#pragma unroll
                for (int ni = 0; ni < 4; ++ni) {
                    const int d = ni * 16 + l16;
                    float f = freqs[n * HD_ + d];
                    float cf = __cosf(f), sf = __sinf(f);
                    float v = acc[mi][ni][r];
                    float o = __shfl_xor(v, 1);     // partner element of the pair
                    acc[mi][ni][r] = (d & 1) ? (v * cf + o * sf)
                                             : (v * cf - o * sf);
                }
            }
    }

    __syncthreads();   // all waves done with As/Bs before smem reuse

    if (by < 16) {
        // Q/K: stage bf16 tile (stride 128), write [bh][n][d] with head-split 16B stores
        u16* Cs = smem;
#pragma unroll
        for (int mi = 0; mi < 4; ++mi)
#pragma unroll
            for (int ni = 0; ni < 4; ++ni)
#pragma unroll
                for (int r = 0; r < 4; ++r)
                    Cs[(wm + mi * 16 + quad * 4 + r) * 128 + wn + ni * 16 + l16] =
                        f2bu(acc[mi][ni][r]);
        __syncthreads();
        u16* dstbase = (by < 8) ? Qg : Kg;
        const int orow = t >> 4;          // 0..15
        const int oc = (t & 15) * 8;      // 0..120
#pragma unroll
        for (int rr = 0; rr < 8; ++rr) {
            const int row = rr * 16 + orow;
            const int n = row0 + row;
            const int b = n >> 11, nn = n & (N_ - 1);
            const int c = col0 + oc;
            const int h = (c & 1023) >> 6, d = c & 63;
            u16* dst = dstbase + (((size_t)(b * H_ + h)) * N_ + nn) * HD_ + d;
            *(uint4*)dst = *(const uint4*)(Cs + row * 128 + oc);
        }
    } else {
        // V: stage bf16 tile at odd stride 137 (transposed scalar reads conflict-free),
        // write V^T [bh][d][n] as 16B chunks along n
        u16* Cs = smem;
#pragma unroll
        for (int mi = 0; mi < 4; ++mi)
#pragma unroll
            for (int ni = 0; ni < 4; ++ni)
#pragma unroll
                for (int r = 0; r < 4; ++r)
                    Cs[(wm + mi * 16 + quad * 4 + r) * 137 + wn + ni * 16 + l16] =
                        f2bu(acc[mi][ni][r]);
        __syncthreads();
        const int b = row0 >> 11;
        const int nn0 = row0 & (N_ - 1);
        const int n8 = (t & 15) * 8;      // 0..120
        const int d0 = t >> 4;            // 0..15
#pragma unroll
        for (int dd = 0; dd < 8; ++dd) {
            const int d = d0 + dd * 16;   // tile-local col 0..127
            const int c = col0 + d;
            const int h = (c & 1023) >> 6, dch = c & 63;
            u16 tmp[8];
#pragma unroll
            for (int i = 0; i < 8; ++i) tmp[i] = Cs[(n8 + i) * 137 + d];
            u16* dst = Vtg + (((size_t)(b * H_ + h)) * HD_ + dch) * N_ + nn0 + n8;
            *(uint4*)dst = *(const uint4*)tmp;
        }
    }
}

// ============  out-proj GEMM: C(fp32) = attn[4096][1024] * wot[1024][1024]^T + bias  ============
// tile 128x64, grid (32,16) = 512 blocks (2/CU); 4 waves, each 64x32 (4x2 accs)
__global__ __launch_bounds__(256) void k_gemm_out(const u16* __restrict__ A,
                                                  const u16* __restrict__ Bt,
                                                  const float* __restrict__ bias,
                                                  float* __restrict__ C) {
    __shared__ u16 smem[16384];           // As 8192 | Bs 4096 (u16); epilogue fp32 128x64 = 32KB
    u16* As = smem;
    u16* Bs = smem + 8192;
    const int t = threadIdx.x;
    const int wave = t >> 6, lane = t & 63;
    const int quad = lane >> 4, l16 = lane & 15;
    const int wm = (wave >> 1) * 64, wn = (wave & 1) * 32;
    const int row0 = blockIdx.x * 128, col0 = blockIdx.y * 64;

    floatx4 acc[4][2] = {};

    const int srow = t >> 3;
    const int scol = (((t & 7) ^ (srow & 7)) * 8);
    const u16* gA = A + (size_t)(row0 + srow) * 1024 + scol;
    const u16* gB = Bt + (size_t)(col0 + srow) * 1024 + scol;
    u16* lA = As + t * 8;
    u16* lB = Bs + t * 8;

    for (int k0 = 0; k0 < 1024; k0 += 64) {
        __syncthreads();
#pragma unroll
        for (int rr = 0; rr < 4; ++rr)
            glds16(gA + (size_t)(rr * 32) * 1024 + k0, lA + rr * 2048);
#pragma unroll
        for (int rr = 0; rr < 2; ++rr)
            glds16(gB + (size_t)(rr * 32) * 1024 + k0, lB + rr * 2048);
        __syncthreads();
#pragma unroll
        for (int c = 0; c < 2; ++c) {
            short8 af[4], bfr[2];
            const int swz = ((4 * c + quad) ^ (l16 & 7)) * 8;
#pragma unroll
            for (int mi = 0; mi < 4; ++mi)
                af[mi] = *(const short8*)(As + (wm + mi * 16 + l16) * 64 + swz);
#pragma unroll
            for (int ni = 0; ni < 2; ++ni)
                bfr[ni] = *(const short8*)(Bs + (wn + ni * 16 + l16) * 64 + swz);
#pragma unroll
            for (int mi = 0; mi < 4; ++mi)
#pragma unroll
                for (int ni = 0; ni < 2; ++ni)
                    acc[mi][ni] = __builtin_amdgcn_mfma_f32_16x16x32_bf16(
                        af[mi], bfr[ni], acc[mi][ni], 0, 0, 0);
        }
    }

    float bv2[2];
#pragma unroll
    for (int ni = 0; ni < 2; ++ni) bv2[ni] = bias[col0 + wn + ni * 16 + l16];

    __syncthreads();
    float* Cf = (float*)smem;             // 128 x 64 fp32
#pragma unroll
    for (int mi = 0; mi < 4; ++mi)
#pragma unroll
        for (int ni = 0; ni < 2; ++ni)
#pragma unroll
            for (int r = 0; r < 4; ++r)
                Cf[(wm + mi * 16 + quad * 4 + r) * 64 + wn + ni * 16 + l16] =
                    acc[mi][ni][r] + bv2[ni];
    __syncthreads();
    const int orow = t >> 4;              // 0..15
    const int oc = (t & 15) * 4;          // 0..60
#pragma unroll
    for (int rr = 0; rr < 8; ++rr) {
        const int row = rr * 16 + orow;
        *(float4*)(C + (size_t)(row0 + row) * 1024 + col0 + oc) =
            *(const float4*)(Cf + row * 64 + oc);
    }
}

// ==========  sliding-window flash attention; block = (64 q-rows, h, b)  ==========
__global__ __launch_bounds__(256) void k_attn(const u16* __restrict__ Qg,
                                              const u16* __restrict__ Kg,
                                              const u16* __restrict__ Vtg,
                                              u16* __restrict__ Og) {
    __shared__ u16 Qs[64 * 72];
    __shared__ u16 Ks[64 * 72];
    __shared__ u16 Vs[64 * 72];
    __shared__ u16 Ps[4 * 16 * 72];
    const int t = threadIdx.x;
    const int wave = t >> 6, lane = t & 63;
    const int quad = lane >> 4, l16 = lane & 15;
    const int q0 = blockIdx.x * 64;
    const int h = blockIdx.y, b = blockIdx.z;
    const size_t bh = (size_t)(b * H_ + h);

    {
        const int srow = t >> 2;
        const int su = (t & 3) * 16;
        const u16* qp = Qg + (bh * N_ + q0 + srow) * HD_ + su;
        uint4 v0 = *(const uint4*)(qp);
        uint4 v1 = *(const uint4*)(qp + 8);
        *(uint4*)(Qs + srow * 72 + su) = v0;
        *(uint4*)(Qs + srow * 72 + su + 8) = v1;
    }
    __syncthreads();

    floatx4 oacc[4] = {};
    float mrow[4], lrow[4];
#pragma unroll
    for (int r = 0; r < 4; ++r) { mrow[r] = -1e30f; lrow[r] = 0.f; }
    const int qrow_base = q0 + wave * 16 + quad * 4;

    for (int tt = 0; tt < 5; ++tt) {
        const int j0 = q0 - 128 + tt * 64;
        if (j0 < 0 || j0 >= N_) continue;
        const bool need_mask = (tt == 0) || (tt == 4);  // interior tiles always in-window
        __syncthreads();
        {
            const int srow = t >> 2;
            const int su = (t & 3) * 16;
            const u16* kp = Kg + (bh * N_ + j0 + srow) * HD_ + su;
            uint4 k0v = *(const uint4*)(kp);
            uint4 k1v = *(const uint4*)(kp + 8);
            const u16* vp = Vtg + (bh * HD_ + srow) * N_ + j0 + su;
            uint4 v0v = *(const uint4*)(vp);
            uint4 v1v = *(const uint4*)(vp + 8);
            *(uint4*)(Ks + srow * 72 + su) = k0v;
            *(uint4*)(Ks + srow * 72 + su + 8) = k1v;
            *(uint4*)(Vs + srow * 72 + su) = v0v;
            *(uint4*)(Vs + srow * 72 + su + 8) = v1v;
        }
        __syncthreads();

        floatx4 s[4] = {};
        short8 aq0 = *(const short8*)(Qs + (wave * 16 + l16) * 72 + quad * 8);
        short8 aq1 = *(const short8*)(Qs + (wave * 16 + l16) * 72 + 32 + quad * 8);
#pragma unroll
        for (int ni = 0; ni < 4; ++ni) {
            short8 bk0 = *(const short8*)(Ks + (ni * 16 + l16) * 72 + quad * 8);
            short8 bk1 = *(const short8*)(Ks + (ni * 16 + l16) * 72 + 32 + quad * 8);
            s[ni] = __builtin_amdgcn_mfma_f32_16x16x32_bf16(aq0, bk0, s[ni], 0, 0, 0);
            s[ni] = __builtin_amdgcn_mfma_f32_16x16x32_bf16(aq1, bk1, s[ni], 0, 0, 0);
        }
        if (need_mask) {
#pragma unroll
            for (int ni = 0; ni < 4; ++ni)
#pragma unroll
                for (int r = 0; r < 4; ++r) {
                    int dj = (j0 + ni * 16 + l16) - (qrow_base + r);
                    bool valid = (dj >= -HALF_W) && (dj <= HALF_W);
                    s[ni][r] = valid ? s[ni][r] * 0.125f : -1e30f;
                }
        } else {
#pragma unroll
            for (int ni = 0; ni < 4; ++ni)
#pragma unroll
                for (int r = 0; r < 4; ++r) s[ni][r] *= 0.125f;
        }
        float newm[4];
#pragma unroll
        for (int r = 0; r < 4; ++r) {
            float v = fmaxf(fmaxf(s[0][r], s[1][r]), fmaxf(s[2][r], s[3][r]));
            v = fmaxf(v, __shfl_xor(v, 1)); v = fmaxf(v, __shfl_xor(v, 2));
            v = fmaxf(v, __shfl_xor(v, 4)); v = fmaxf(v, __shfl_xor(v, 8));
            newm[r] = fmaxf(mrow[r], v);
        }
#pragma unroll
        for (int ni = 0; ni < 4; ++ni)
#pragma unroll
            for (int r = 0; r < 4; ++r)
                s[ni][r] = __expf(s[ni][r] - newm[r]);
#pragma unroll
        for (int r = 0; r < 4; ++r) {
            float v = s[0][r] + s[1][r] + s[2][r] + s[3][r];
            v += __shfl_xor(v, 1); v += __shfl_xor(v, 2);
            v += __shfl_xor(v, 4); v += __shfl_xor(v, 8);
            float alpha = __expf(mrow[r] - newm[r]);
            lrow[r] = lrow[r] * alpha + v;
            mrow[r] = newm[r];
#pragma unroll
            for (int ni = 0; ni < 4; ++ni) oacc[ni][r] *= alpha;
        }
        u16* pw = Ps + wave * 16 * 72;
#pragma unroll
        for (int ni = 0; ni < 4; ++ni)
#pragma unroll
            for (int r = 0; r < 4; ++r)
                pw[(quad * 4 + r) * 72 + ni * 16 + l16] = f2bu(s[ni][r]);
        __syncthreads();
#pragma unroll
        for (int c = 0; c < 2; ++c) {
            short8 pf = *(const short8*)(pw + l16 * 72 + 32 * c + quad * 8);
#pragma unroll
            for (int ni = 0; ni < 4; ++ni) {
                short8 vf = *(const short8*)(Vs + (ni * 16 + l16) * 72 + 32 * c + quad * 8);
                oacc[ni] = __builtin_amdgcn_mfma_f32_16x16x32_bf16(pf, vf, oacc[ni], 0, 0, 0);
            }
        }
    }
    u16* outp = Og + ((size_t)b * N_ + q0 + wave * 16 + quad * 4) * INNER_ + h * HD_;
#pragma unroll
    for (int ni = 0; ni < 4; ++ni)
#pragma unroll
        for (int r = 0; r < 4; ++r) {
            float v = oacc[ni][r] / lrow[r];
            outp[(size_t)r * INNER_ + ni * 16 + l16] = f2bu(v);
        }
}

// =====================  host side  =====================
extern "C" void kernel_launch(void* const* d_in, const int* in_sizes, int n_in,
                              void* d_out, int out_size, void* d_ws, size_t ws_size,
                              hipStream_t stream) {
    const float* x     = (const float*)d_in[0];
    const float* freqs = (const float*)d_in[2];
    const float* Wq    = (const float*)d_in[3];
    const float* bq    = (const float*)d_in[4];
    const float* Wk    = (const float*)d_in[5];
    const float* bk    = (const float*)d_in[6];
    const float* Wv    = (const float*)d_in[7];
    const float* bv    = (const float*)d_in[8];
    const float* Wo    = (const float*)d_in[9];
    const float* bo    = (const float*)d_in[10];

    char* w = (char*)d_ws;
    u16* xb       = (u16*)w;  w += (size_t)4096 * 1024 * 2;
    u16* wqkvt    = (u16*)w;  w += (size_t)3072 * 1024 * 2;
    u16* wot      = (u16*)w;  w += (size_t)1024 * 1024 * 2;
    float* bias_qkv = (float*)w; w += 3072 * 4;
    float* bias_o   = (float*)w; w += 1024 * 4;
    u16* Qb       = (u16*)w;  w += (size_t)B_ * H_ * N_ * HD_ * 2;
    u16* Kb       = (u16*)w;  w += (size_t)B_ * H_ * N_ * HD_ * 2;
    u16* Vtb      = (u16*)w;  w += (size_t)B_ * H_ * N_ * HD_ * 2;
    u16* attn     = (u16*)w;  w += (size_t)4096 * 1024 * 2;

    k_convert_x<<<4096, 256, 0, stream>>>(x, xb, 4096 * 1024);
    k_transpose_w4<<<dim3(16, 16, 4), 256, 0, stream>>>(Wq, Wk, Wv, Wo, wqkvt, wot);
    k_pack_bias<<<4, 256, 0, stream>>>(bq, bk, bv, bo, bias_qkv, bias_o);

    k_gemm_qkv<<<dim3(32, 24), 256, 0, stream>>>(xb, wqkvt, bias_qkv, freqs,
                                                 Qb, Kb, Vtb);
    k_attn<<<dim3(32, 16, 2), 256, 0, stream>>>(Qb, Kb, Vtb, attn);
    k_gemm_out<<<dim3(32, 16), 256, 0, stream>>>(attn, wot, bias_o, (float*)d_out);
}

// Round 5
// 170.951 us; speedup vs baseline: 1.8199x; 1.1407x over previous
//
#include <hip/hip_runtime.h>
#include <hip/hip_bf16.h>
#include <stdint.h>

#define B_ 2
#define N_ 2048
#define D_ 1024
#define H_ 16
#define HD_ 64
#define INNER_ 1024
#define HALF_W 128

typedef unsigned short u16;
typedef __attribute__((ext_vector_type(8))) short short8;
typedef __attribute__((ext_vector_type(4))) float floatx4;

// ---- bf16 <-> f32 bit helpers ----
__device__ inline u16 f2bu(float x) {
    union { float f; uint32_t u; } c; c.f = x;
    uint32_t u = c.u;
    uint32_t r = (u + 0x7FFFu + ((u >> 16) & 1u)) >> 16;
    return (u16)r;
}
__device__ inline float bu2f(u16 v) {
    union { float f; uint32_t u; } c; c.u = ((uint32_t)v) << 16;
    return c.f;
}

// ---- async global->LDS, 16B per lane (dest = wave-uniform base + lane*16) ----
__device__ inline void glds16(const u16* g, u16* l) {
    __builtin_amdgcn_global_load_lds(
        (const __attribute__((address_space(1))) uint32_t*)g,
        (__attribute__((address_space(3))) uint32_t*)l, 16, 0, 0);
}

// =====================  convert x: fp32 -> bf16  =====================
__global__ __launch_bounds__(256) void k_convert_x(const float* __restrict__ x,
                                                   u16* __restrict__ xb, int n) {
    int i = (blockIdx.x * 256 + threadIdx.x) * 4;
    if (i < n) {
        float4 v = *(const float4*)(x + i);
        uint32_t p0 = (uint32_t)f2bu(v.x) | ((uint32_t)f2bu(v.y) << 16);
        uint32_t p1 = (uint32_t)f2bu(v.z) | ((uint32_t)f2bu(v.w) << 16);
        uint2 o; o.x = p0; o.y = p1;
        *(uint2*)(xb + i) = o;
    }
}

// ====  transpose+convert all 4 weights: fp32 [1024][1024] -> bf16 [n][k], z picks W  ====
__global__ __launch_bounds__(256) void k_transpose_w4(const float* __restrict__ Wq,
                                                      const float* __restrict__ Wk,
                                                      const float* __restrict__ Wv,
                                                      const float* __restrict__ Wo,
                                                      u16* __restrict__ wqkvt,
                                                      u16* __restrict__ wot) {
    __shared__ float ts[64][65];
    const int z = blockIdx.z;
    const float* src = (z == 0) ? Wq : (z == 1) ? Wk : (z == 2) ? Wv : Wo;
    u16* dst = (z < 3) ? (wqkvt + (size_t)z * 1024 * 1024) : wot;
    const int kb = blockIdx.x, nb = blockIdx.y;
    const int t = threadIdx.x;
    const int row = t >> 2;
    const int c4 = (t & 3) * 16;
    const float* s = src + (size_t)(kb * 64 + row) * 1024 + nb * 64 + c4;
#pragma unroll
    for (int i = 0; i < 16; i += 4) {
        float4 v = *(const float4*)(s + i);
        ts[row][c4 + i] = v.x; ts[row][c4 + i + 1] = v.y;
        ts[row][c4 + i + 2] = v.z; ts[row][c4 + i + 3] = v.w;
    }
    __syncthreads();
    const int n = row;
    u16* d = dst + (size_t)(nb * 64 + n) * 1024 + kb * 64 + c4;
    u16 tmp[16];
#pragma unroll
    for (int i = 0; i < 16; ++i) tmp[i] = f2bu(ts[c4 + i][n]);
    *(uint4*)(d) = *(uint4*)tmp;
    *(uint4*)(d + 8) = *((uint4*)tmp + 1);
}

// =====================  pack biases  =====================
__global__ void k_pack_bias(const float* bq, const float* bk, const float* bv,
                            const float* bo, float* bias_qkv, float* bias_o) {
    int i = blockIdx.x * 256 + threadIdx.x;
    if (i < 1024) {
        bias_qkv[i] = bq[i];
        bias_qkv[1024 + i] = bk[i];
        bias_qkv[2048 + i] = bv[i];
        bias_o[i] = bo[i];
    }
}

// ============  QKV GEMM + bias + scatter epilogue (no RoPE here)  ============
// by 0-7 -> Q, 8-15 -> K (write [bh][n][d]), 16-23 -> V (write V^T [bh][d][n]).
__global__ __launch_bounds__(256, 4) void k_gemm_qkv(const u16* __restrict__ A,
                                                     const u16* __restrict__ Bt,
                                                     const float* __restrict__ bias,
                                                     u16* __restrict__ Qg,
                                                     u16* __restrict__ Kg,
                                                     u16* __restrict__ Vtg) {
    __shared__ u16 smem[128 * 137];              // K-loop: As|Bs; epilogue staging
    u16* As = smem;
    u16* Bs = smem + 128 * 64;
    const int t = threadIdx.x;
    const int wave = t >> 6, lane = t & 63;
    const int quad = lane >> 4, l16 = lane & 15;
    const int wm = (wave >> 1) * 64, wn = (wave & 1) * 64;
    const int by = blockIdx.y;
    const int row0 = blockIdx.x * 128, col0 = by * 128;

    floatx4 acc[4][4] = {};

    const int srow = t >> 3;                       // 0..31
    const int scol = (((t & 7) ^ (srow & 7)) * 8); // XOR-swizzled col chunk
    const u16* gA = A + (size_t)(row0 + srow) * 1024 + scol;
    const u16* gB = Bt + (size_t)(col0 + srow) * 1024 + scol;
    u16* lA = As + t * 8;
    u16* lB = Bs + t * 8;

    for (int k0 = 0; k0 < 1024; k0 += 64) {
        __syncthreads();
#pragma unroll
        for (int rr = 0; rr < 4; ++rr) {
            glds16(gA + (size_t)(rr * 32) * 1024 + k0, lA + rr * 2048);
            glds16(gB + (size_t)(rr * 32) * 1024 + k0, lB + rr * 2048);
        }
        __syncthreads();
#pragma unroll
        for (int c = 0; c < 2; ++c) {
            short8 af[4], bfr[4];
            const int swz = ((4 * c + quad) ^ (l16 & 7)) * 8;
#pragma unroll
            for (int mi = 0; mi < 4; ++mi)
                af[mi] = *(const short8*)(As + (wm + mi * 16 + l16) * 64 + swz);
#pragma unroll
            for (int ni = 0; ni < 4; ++ni)
                bfr[ni] = *(const short8*)(Bs + (wn + ni * 16 + l16) * 64 + swz);
#pragma unroll
            for (int mi = 0; mi < 4; ++mi)
#pragma unroll
                for (int ni = 0; ni < 4; ++ni)
                    acc[mi][ni] = __builtin_amdgcn_mfma_f32_16x16x32_bf16(
                        af[mi], bfr[ni], acc[mi][ni], 0, 0, 0);
        }
    }

#pragma unroll
    for (int ni = 0; ni < 4; ++ni) {
        float bval = bias[col0 + wn + ni * 16 + l16];
#pragma unroll
        for (int mi = 0; mi < 4; ++mi)
#pragma unroll
            for (int r = 0; r < 4; ++r) acc[mi][ni][r] += bval;
    }

    __syncthreads();   // all waves done with As/Bs before smem reuse

    if (by < 16) {
        // Q/K: stage bf16 tile (stride 128), write [bh][n][d] head-split 16B stores
        u16* Cs = smem;
#pragma unroll
        for (int mi = 0; mi < 4; ++mi)
#pragma unroll
            for (int ni = 0; ni < 4; ++ni)
#pragma unroll
                for (int r = 0; r < 4; ++r)
                    Cs[(wm + mi * 16 + quad * 4 + r) * 128 + wn + ni * 16 + l16] =
                        f2bu(acc[mi][ni][r]);
        __syncthreads();
        u16* dstbase = (by < 8) ? Qg : Kg;
        const int orow = t >> 4;          // 0..15
        const int oc = (t & 15) * 8;      // 0..120
#pragma unroll
        for (int rr = 0; rr < 8; ++rr) {
            const int row = rr * 16 + orow;
            const int n = row0 + row;
            const int b = n >> 11, nn = n & (N_ - 1);
            const int c = col0 + oc;
            const int h = (c & 1023) >> 6, d = c & 63;
            u16* dst = dstbase + (((size_t)(b * H_ + h)) * N_ + nn) * HD_ + d;
            *(uint4*)dst = *(const uint4*)(Cs + row * 128 + oc);
        }
    } else {
        // V: stage at odd stride 137, write V^T [bh][d][n] as 16B chunks along n
        u16* Cs = smem;
#pragma unroll
        for (int mi = 0; mi < 4; ++mi)
#pragma unroll
            for (int ni = 0; ni < 4; ++ni)
#pragma unroll
                for (int r = 0; r < 4; ++r)
                    Cs[(wm + mi * 16 + quad * 4 + r) * 137 + wn + ni * 16 + l16] =
                        f2bu(acc[mi][ni][r]);
        __syncthreads();
        const int b = row0 >> 11;
        const int nn0 = row0 & (N_ - 1);
        const int n8 = (t & 15) * 8;      // 0..120
        const int d0 = t >> 4;            // 0..15
#pragma unroll
        for (int dd = 0; dd < 8; ++dd) {
            const int d = d0 + dd * 16;
            const int c = col0 + d;
            const int h = (c & 1023) >> 6, dch = c & 63;
            u16 tmp[8];
#pragma unroll
            for (int i = 0; i < 8; ++i) tmp[i] = Cs[(n8 + i) * 137 + d];
            u16* dst = Vtg + (((size_t)(b * H_ + h)) * HD_ + dch) * N_ + nn0 + n8;
            *(uint4*)dst = *(const uint4*)tmp;
        }
    }
}

// ==========  RoPE in-place on head-0 strips of Q and K (1 MB total)  ==========
__global__ __launch_bounds__(256) void k_rope(u16* __restrict__ Qg,
                                              u16* __restrict__ Kg,
                                              const float* __restrict__ freqs) {
    const int t = threadIdx.x;
    const int n = blockIdx.x * 64 + (t >> 2);
    const int d0 = (t & 3) * 16;
    const int b = blockIdx.z;
    u16* base = (blockIdx.y == 0 ? Qg : Kg) +
                (((size_t)(b * H_)) * N_ + n) * HD_ + d0;   // head 0
    u16 buf[16];
    *(uint4*)buf = *(const uint4*)base;
    *((uint4*)buf + 1) = *(const uint4*)(base + 8);
    const float* f = freqs + n * HD_ + d0;
    u16 outv[16];
#pragma unroll
    for (int i = 0; i < 8; ++i) {
        float fe = f[2 * i], fo = f[2 * i + 1];
        float ve = bu2f(buf[2 * i]), vo = bu2f(buf[2 * i + 1]);
        outv[2 * i]     = f2bu(ve * __cosf(fe) - vo * __sinf(fe));
        outv[2 * i + 1] = f2bu(vo * __cosf(fo) + ve * __sinf(fo));
    }
    *(uint4*)base = *(uint4*)outv;
    *(uint4*)(base + 8) = *((uint4*)outv + 1);
}

// ============  out-proj GEMM: C(fp32) = attn * wot^T + bias; tile 128x64  ============
__global__ __launch_bounds__(256, 4) void k_gemm_out(const u16* __restrict__ A,
                                                     const u16* __restrict__ Bt,
                                                     const float* __restrict__ bias,
                                                     float* __restrict__ C) {
    __shared__ u16 smem[16384];
    u16* As = smem;
    u16* Bs = smem + 8192;
    const int t = threadIdx.x;
    const int wave = t >> 6, lane = t & 63;
    const int quad = lane >> 4, l16 = lane & 15;
    const int wm = (wave >> 1) * 64, wn = (wave & 1) * 32;
    const int row0 = blockIdx.x * 128, col0 = blockIdx.y * 64;

    floatx4 acc[4][2] = {};

    const int srow = t >> 3;
    const int scol = (((t & 7) ^ (srow & 7)) * 8);
    const u16* gA = A + (size_t)(row0 + srow) * 1024 + scol;
    const u16* gB = Bt + (size_t)(col0 + srow) * 1024 + scol;
    u16* lA = As + t * 8;
    u16* lB = Bs + t * 8;

    for (int k0 = 0; k0 < 1024; k0 += 64) {
        __syncthreads();
#pragma unroll
        for (int rr = 0; rr < 4; ++rr)
            glds16(gA + (size_t)(rr * 32) * 1024 + k0, lA + rr * 2048);
#pragma unroll
        for (int rr = 0; rr < 2; ++rr)
            glds16(gB + (size_t)(rr * 32) * 1024 + k0, lB + rr * 2048);
        __syncthreads();
#pragma unroll
        for (int c = 0; c < 2; ++c) {
            short8 af[4], bfr[2];
            const int swz = ((4 * c + quad) ^ (l16 & 7)) * 8;
#pragma unroll
            for (int mi = 0; mi < 4; ++mi)
                af[mi] = *(const short8*)(As + (wm + mi * 16 + l16) * 64 + swz);
#pragma unroll
            for (int ni = 0; ni < 2; ++ni)
                bfr[ni] = *(const short8*)(Bs + (wn + ni * 16 + l16) * 64 + swz);
#pragma unroll
            for (int mi = 0; mi < 4; ++mi)
#pragma unroll
                for (int ni = 0; ni < 2; ++ni)
                    acc[mi][ni] = __builtin_amdgcn_mfma_f32_16x16x32_bf16(
                        af[mi], bfr[ni], acc[mi][ni], 0, 0, 0);
        }
    }

    float bv2[2];
#pragma unroll
    for (int ni = 0; ni < 2; ++ni) bv2[ni] = bias[col0 + wn + ni * 16 + l16];

    __syncthreads();
    float* Cf = (float*)smem;
#pragma unroll
    for (int mi = 0; mi < 4; ++mi)
#pragma unroll
        for (int ni = 0; ni < 2; ++ni)
#pragma unroll
            for (int r = 0; r < 4; ++r)
                Cf[(wm + mi * 16 + quad * 4 + r) * 64 + wn + ni * 16 + l16] =
                    acc[mi][ni][r] + bv2[ni];
    __syncthreads();
    const int orow = t >> 4;
    const int oc = (t & 15) * 4;
#pragma unroll
    for (int rr = 0; rr < 8; ++rr) {
        const int row = rr * 16 + orow;
        *(float4*)(C + (size_t)(row0 + row) * 1024 + col0 + oc) =
            *(const float4*)(Cf + row * 64 + oc);
    }
}

// ==========  sliding-window flash attention (no-max softmax, deferred sum)  ==========
// block = (64 q-rows, h, b); staging via global_load_lds + XOR swizzle; 2 barriers/tile.
__global__ __launch_bounds__(256, 4) void k_attn(const u16* __restrict__ Qg,
                                                 const u16* __restrict__ Kg,
                                                 const u16* __restrict__ Vtg,
                                                 u16* __restrict__ Og) {
    __shared__ u16 Qs[64 * 64];
    __shared__ u16 Ks[64 * 64];
    __shared__ u16 Vs[64 * 64];
    __shared__ u16 Ps[4 * 16 * 72];
    const int t = threadIdx.x;
    const int wave = t >> 6, lane = t & 63;
    const int quad = lane >> 4, l16 = lane & 15;
    const int q0 = blockIdx.x * 64;
    const int h = blockIdx.y, b = blockIdx.z;
    const size_t bh = (size_t)(b * H_ + h);

    const int srow = t >> 3;                        // 0..31
    const int sch = ((t & 7) ^ (srow & 7)) * 8;     // XOR-swizzled col chunk

    // stage Q (2 glds16/thread); drained by tile-0's post-stage barrier
    {
        const u16* qg = Qg + (bh * N_ + q0 + srow) * HD_ + sch;
        glds16(qg, Qs + t * 8);
        glds16(qg + 32 * HD_, Qs + 2048 + t * 8);
    }
    const u16* kg0 = Kg + (bh * N_ + srow) * HD_ + sch;   // + j0*HD_
    const u16* vg0 = Vtg + (bh * HD_ + srow) * N_ + sch;  // + j0

    floatx4 oacc[4] = {};
    float lsum[4] = {0.f, 0.f, 0.f, 0.f};
    const int qrow_base = q0 + wave * 16 + quad * 4;
    const int swz0 = (quad ^ (l16 & 7)) * 8;
    const int swz1 = ((4 + quad) ^ (l16 & 7)) * 8;

    for (int tt = 0; tt < 5; ++tt) {
        const int j0 = q0 - 128 + tt * 64;
        if (j0 < 0 || j0 >= N_) continue;           // uniform across block
        const bool need_mask = (tt == 0) || (tt == 4);
        __syncthreads();                             // prev tile's K/V reads done
        glds16(kg0 + (size_t)j0 * HD_, Ks + t * 8);
        glds16(kg0 + (size_t)(j0 + 32) * HD_, Ks + 2048 + t * 8);
        glds16(vg0 + j0, Vs + t * 8);
        glds16(vg0 + j0 + 32 * N_, Vs + 2048 + t * 8);
        __syncthreads();                             // drain vmcnt

        floatx4 s[4] = {};
        short8 aq0 = *(const short8*)(Qs + (wave * 16 + l16) * 64 + swz0);
        short8 aq1 = *(const short8*)(Qs + (wave * 16 + l16) * 64 + swz1);
#pragma unroll
        for (int ni = 0; ni < 4; ++ni) {
            short8 bk0 = *(const short8*)(Ks + (ni * 16 + l16) * 64 + swz0);
            short8 bk1 = *(const short8*)(Ks + (ni * 16 + l16) * 64 + swz1);
            s[ni] = __builtin_amdgcn_mfma_f32_16x16x32_bf16(aq0, bk0, s[ni], 0, 0, 0);
            s[ni] = __builtin_amdgcn_mfma_f32_16x16x32_bf16(aq1, bk1, s[ni], 0, 0, 0);
        }
        // exp(s/8); masked -> 0. Inputs bounded (|s/8| < ~3) so no max-subtraction.
        if (need_mask) {
#pragma unroll
            for (int ni = 0; ni < 4; ++ni)
#pragma unroll
                for (int r = 0; r < 4; ++r) {
                    int dj = (j0 + ni * 16 + l16) - (qrow_base + r);
                    bool valid = (dj >= -HALF_W) && (dj <= HALF_W);
                    s[ni][r] = valid ? __expf(s[ni][r] * 0.125f) : 0.f;
                }
        } else {
#pragma unroll
            for (int ni = 0; ni < 4; ++ni)
#pragma unroll
                for (int r = 0; r < 4; ++r) s[ni][r] = __expf(s[ni][r] * 0.125f);
        }
#pragma unroll
        for (int r = 0; r < 4; ++r)
            lsum[r] += s[0][r] + s[1][r] + s[2][r] + s[3][r];
        // P -> wave-private LDS (no barrier needed; same-wave write->read)
        u16* pw = Ps + wave * 16 * 72;
#pragma unroll
        for (int ni = 0; ni < 4; ++ni)
#pragma unroll
            for (int r = 0; r < 4; ++r)
                pw[(quad * 4 + r) * 72 + ni * 16 + l16] = f2bu(s[ni][r]);
#pragma unroll
        for (int c = 0; c < 2; ++c) {
            short8 pf = *(const short8*)(pw + l16 * 72 + 32 * c + quad * 8);
            const int swz = c ? swz1 : swz0;
#pragma unroll
            for (int ni = 0; ni < 4; ++ni) {
                short8 vf = *(const short8*)(Vs + (ni * 16 + l16) * 64 + swz);
                oacc[ni] = __builtin_amdgcn_mfma_f32_16x16x32_bf16(pf, vf, oacc[ni], 0, 0, 0);
            }
        }
    }
    // one cross-lane reduction at the end
    float linv[4];
#pragma unroll
    for (int r = 0; r < 4; ++r) {
        float v = lsum[r];
        v += __shfl_xor(v, 1); v += __shfl_xor(v, 2);
        v += __shfl_xor(v, 4); v += __shfl_xor(v, 8);
        linv[r] = 1.0f / v;
    }
    u16* outp = Og + ((size_t)b * N_ + q0 + wave * 16 + quad * 4) * INNER_ + h * HD_;
#pragma unroll
    for (int ni = 0; ni < 4; ++ni)
#pragma unroll
        for (int r = 0; r < 4; ++r)
            outp[(size_t)r * INNER_ + ni * 16 + l16] = f2bu(oacc[ni][r] * linv[r]);
}

// =====================  host side  =====================
extern "C" void kernel_launch(void* const* d_in, const int* in_sizes, int n_in,
                              void* d_out, int out_size, void* d_ws, size_t ws_size,
                              hipStream_t stream) {
    const float* x     = (const float*)d_in[0];
    const float* freqs = (const float*)d_in[2];
    const float* Wq    = (const float*)d_in[3];
    const float* bq    = (const float*)d_in[4];
    const float* Wk    = (const float*)d_in[5];
    const float* bk    = (const float*)d_in[6];
    const float* Wv    = (const float*)d_in[7];
    const float* bv    = (const float*)d_in[8];
    const float* Wo    = (const float*)d_in[9];
    const float* bo    = (const float*)d_in[10];

    char* w = (char*)d_ws;
    u16* xb       = (u16*)w;  w += (size_t)4096 * 1024 * 2;
    u16* wqkvt    = (u16*)w;  w += (size_t)3072 * 1024 * 2;
    u16* wot      = (u16*)w;  w += (size_t)1024 * 1024 * 2;
    float* bias_qkv = (float*)w; w += 3072 * 4;
    float* bias_o   = (float*)w; w += 1024 * 4;
    u16* Qb       = (u16*)w;  w += (size_t)B_ * H_ * N_ * HD_ * 2;
    u16* Kb       = (u16*)w;  w += (size_t)B_ * H_ * N_ * HD_ * 2;
    u16* Vtb      = (u16*)w;  w += (size_t)B_ * H_ * N_ * HD_ * 2;
    u16* attn     = (u16*)w;  w += (size_t)4096 * 1024 * 2;

    k_convert_x<<<4096, 256, 0, stream>>>(x, xb, 4096 * 1024);
    k_transpose_w4<<<dim3(16, 16, 4), 256, 0, stream>>>(Wq, Wk, Wv, Wo, wqkvt, wot);
    k_pack_bias<<<4, 256, 0, stream>>>(bq, bk, bv, bo, bias_qkv, bias_o);

    k_gemm_qkv<<<dim3(32, 24), 256, 0, stream>>>(xb, wqkvt, bias_qkv, Qb, Kb, Vtb);
    k_rope<<<dim3(32, 2, 2), 256, 0, stream>>>(Qb, Kb, freqs);
    k_attn<<<dim3(32, 16, 2), 256, 0, stream>>>(Qb, Kb, Vtb, attn);
    k_gemm_out<<<dim3(32, 16), 256, 0, stream>>>(attn, wot, bias_o, (float*)d_out);
}

// Round 6
// 162.783 us; speedup vs baseline: 1.9112x; 1.0502x over previous
//
#include <hip/hip_runtime.h>
#include <hip/hip_bf16.h>
#include <stdint.h>

#define B_ 2
#define N_ 2048
#define D_ 1024
#define H_ 16
#define HD_ 64
#define INNER_ 1024
#define HALF_W 128

typedef unsigned short u16;
typedef __attribute__((ext_vector_type(8))) short short8;
typedef __attribute__((ext_vector_type(4))) float floatx4;

// ---- bf16 <-> f32 bit helpers ----
__device__ inline u16 f2bu(float x) {
    union { float f; uint32_t u; } c; c.f = x;
    uint32_t u = c.u;
    uint32_t r = (u + 0x7FFFu + ((u >> 16) & 1u)) >> 16;
    return (u16)r;
}
__device__ inline float bu2f(u16 v) {
    union { float f; uint32_t u; } c; c.u = ((uint32_t)v) << 16;
    return c.f;
}

// ---- async global->LDS, 16B per lane (dest = wave-uniform base + lane*16) ----
__device__ inline void glds16(const u16* g, u16* l) {
    __builtin_amdgcn_global_load_lds(
        (const __attribute__((address_space(1))) uint32_t*)g,
        (__attribute__((address_space(3))) uint32_t*)l, 16, 0, 0);
}

// =========  prep: W transposes (blocks 0-1023) | x convert (1024-2047) | bias (2048)  =========
__global__ __launch_bounds__(256) void k_prep(const float* __restrict__ x,
                                              const float* __restrict__ Wq,
                                              const float* __restrict__ Wk,
                                              const float* __restrict__ Wv,
                                              const float* __restrict__ Wo,
                                              const float* __restrict__ bq,
                                              const float* __restrict__ bk,
                                              const float* __restrict__ bv,
                                              const float* __restrict__ bo,
                                              u16* __restrict__ xb,
                                              u16* __restrict__ wqkvt,
                                              u16* __restrict__ wot,
                                              float* __restrict__ bias_qkv,
                                              float* __restrict__ bias_o) {
    __shared__ float ts[64][65];
    const int bx = blockIdx.x;
    const int t = threadIdx.x;
    if (bx < 1024) {
        // transpose+convert one 64x64 tile of one weight
        const int z = bx >> 8, w = bx & 255;
        const int kb = w & 15, nb = w >> 4;
        const float* src = (z == 0) ? Wq : (z == 1) ? Wk : (z == 2) ? Wv : Wo;
        u16* dst = (z < 3) ? (wqkvt + (size_t)z * 1024 * 1024) : wot;
        const int row = t >> 2;
        const int c4 = (t & 3) * 16;
        const float* s = src + (size_t)(kb * 64 + row) * 1024 + nb * 64 + c4;
#pragma unroll
        for (int i = 0; i < 16; i += 4) {
            float4 v = *(const float4*)(s + i);
            ts[row][c4 + i] = v.x; ts[row][c4 + i + 1] = v.y;
            ts[row][c4 + i + 2] = v.z; ts[row][c4 + i + 3] = v.w;
        }
        __syncthreads();
        const int n = row;
        u16* d = dst + (size_t)(nb * 64 + n) * 1024 + kb * 64 + c4;
        u16 tmp[16];
#pragma unroll
        for (int i = 0; i < 16; ++i) tmp[i] = f2bu(ts[c4 + i][n]);
        *(uint4*)(d) = *(uint4*)tmp;
        *(uint4*)(d + 8) = *((uint4*)tmp + 1);
    } else if (bx < 2048) {
        // convert x fp32 -> bf16, 4096 floats per block, coalesced float4
        const int base = (bx - 1024) * 4096 + t * 4;
#pragma unroll
        for (int it = 0; it < 4; ++it) {
            const int i = base + it * 1024;
            float4 v = *(const float4*)(x + i);
            uint32_t p0 = (uint32_t)f2bu(v.x) | ((uint32_t)f2bu(v.y) << 16);
            uint32_t p1 = (uint32_t)f2bu(v.z) | ((uint32_t)f2bu(v.w) << 16);
            uint2 o; o.x = p0; o.y = p1;
            *(uint2*)(xb + i) = o;
        }
    } else {
        // pack biases
#pragma unroll
        for (int it = 0; it < 4; ++it) {
            const int i = t + it * 256;
            bias_qkv[i] = bq[i];
            bias_qkv[1024 + i] = bk[i];
            bias_qkv[2048 + i] = bv[i];
            bias_o[i] = bo[i];
        }
    }
}

// ============  QKV GEMM + bias + fused-RoPE scatter epilogue  ============
// by 0-7 -> Q, 8-15 -> K (write [bh][n][d]; RoPE applied to head-0 cols in store path),
// by 16-23 -> V (write V^T [bh][d][n]).
__global__ __launch_bounds__(256, 4) void k_gemm_qkv(const u16* __restrict__ A,
                                                     const u16* __restrict__ Bt,
                                                     const float* __restrict__ bias,
                                                     const float* __restrict__ freqs,
                                                     u16* __restrict__ Qg,
                                                     u16* __restrict__ Kg,
                                                     u16* __restrict__ Vtg) {
    __shared__ u16 smem[128 * 137];              // K-loop: As|Bs; epilogue staging
    u16* As = smem;
    u16* Bs = smem + 128 * 64;
    const int t = threadIdx.x;
    const int wave = t >> 6, lane = t & 63;
    const int quad = lane >> 4, l16 = lane & 15;
    const int wm = (wave >> 1) * 64, wn = (wave & 1) * 64;
    const int by = blockIdx.y;
    const int row0 = blockIdx.x * 128, col0 = by * 128;

    floatx4 acc[4][4] = {};

    const int srow = t >> 3;                       // 0..31
    const int scol = (((t & 7) ^ (srow & 7)) * 8); // XOR-swizzled col chunk
    const u16* gA = A + (size_t)(row0 + srow) * 1024 + scol;
    const u16* gB = Bt + (size_t)(col0 + srow) * 1024 + scol;
    u16* lA = As + t * 8;
    u16* lB = Bs + t * 8;

    for (int k0 = 0; k0 < 1024; k0 += 64) {
        __syncthreads();
#pragma unroll
        for (int rr = 0; rr < 4; ++rr) {
            glds16(gA + (size_t)(rr * 32) * 1024 + k0, lA + rr * 2048);
            glds16(gB + (size_t)(rr * 32) * 1024 + k0, lB + rr * 2048);
        }
        __syncthreads();
#pragma unroll
        for (int c = 0; c < 2; ++c) {
            short8 af[4], bfr[4];
            const int swz = ((4 * c + quad) ^ (l16 & 7)) * 8;
#pragma unroll
            for (int mi = 0; mi < 4; ++mi)
                af[mi] = *(const short8*)(As + (wm + mi * 16 + l16) * 64 + swz);
#pragma unroll
            for (int ni = 0; ni < 4; ++ni)
                bfr[ni] = *(const short8*)(Bs + (wn + ni * 16 + l16) * 64 + swz);
#pragma unroll
            for (int mi = 0; mi < 4; ++mi)
#pragma unroll
                for (int ni = 0; ni < 4; ++ni)
                    acc[mi][ni] = __builtin_amdgcn_mfma_f32_16x16x32_bf16(
                        af[mi], bfr[ni], acc[mi][ni], 0, 0, 0);
        }
    }

#pragma unroll
    for (int ni = 0; ni < 4; ++ni) {
        float bval = bias[col0 + wn + ni * 16 + l16];
#pragma unroll
        for (int mi = 0; mi < 4; ++mi)
#pragma unroll
            for (int r = 0; r < 4; ++r) acc[mi][ni][r] += bval;
    }

    __syncthreads();   // all waves done with As/Bs before smem reuse

    if (by < 16) {
        // Q/K: stage bf16 tile (stride 128), write [bh][n][d] head-split 16B stores.
        // RoPE fused here: head-0 strip = (by==0 || by==8) && tile-col < 64.
        u16* Cs = smem;
#pragma unroll
        for (int mi = 0; mi < 4; ++mi)
#pragma unroll
            for (int ni = 0; ni < 4; ++ni)
#pragma unroll
                for (int r = 0; r < 4; ++r)
                    Cs[(wm + mi * 16 + quad * 4 + r) * 128 + wn + ni * 16 + l16] =
                        f2bu(acc[mi][ni][r]);
        __syncthreads();
        u16* dstbase = (by < 8) ? Qg : Kg;
        const bool rope_blk = (by == 0 || by == 8);
        const int orow = t >> 4;          // 0..15
        const int oc = (t & 15) * 8;      // 0..120
#pragma unroll
        for (int rr = 0; rr < 8; ++rr) {
            const int row = rr * 16 + orow;
            const int n = row0 + row;
            const int b = n >> 11, nn = n & (N_ - 1);
            const int c = col0 + oc;
            const int h = (c & 1023) >> 6, d = c & 63;
            uint4 val = *(const uint4*)(Cs + row * 128 + oc);
            if (rope_blk && oc < 64) {
                const float* f = freqs + (size_t)nn * HD_ + oc;
                u16* pv = (u16*)&val;
#pragma unroll
                for (int i = 0; i < 4; ++i) {
                    float fe = f[2 * i], fo = f[2 * i + 1];
                    float ve = bu2f(pv[2 * i]), vo = bu2f(pv[2 * i + 1]);
                    pv[2 * i]     = f2bu(ve * __cosf(fe) - vo * __sinf(fe));
                    pv[2 * i + 1] = f2bu(vo * __cosf(fo) + ve * __sinf(fo));
                }
            }
            u16* dst = dstbase + (((size_t)(b * H_ + h)) * N_ + nn) * HD_ + d;
            *(uint4*)dst = val;
        }
    } else {
        // V: stage at odd stride 137, write V^T [bh][d][n] as 16B chunks along n
        u16* Cs = smem;
#pragma unroll
        for (int mi = 0; mi < 4; ++mi)
#pragma unroll
            for (int ni = 0; ni < 4; ++ni)
#pragma unroll
                for (int r = 0; r < 4; ++r)
                    Cs[(wm + mi * 16 + quad * 4 + r) * 137 + wn + ni * 16 + l16] =
                        f2bu(acc[mi][ni][r]);
        __syncthreads();
        const int b = row0 >> 11;
        const int nn0 = row0 & (N_ - 1);
        const int n8 = (t & 15) * 8;      // 0..120
        const int d0 = t >> 4;            // 0..15
#pragma unroll
        for (int dd = 0; dd < 8; ++dd) {
            const int d = d0 + dd * 16;
            const int c = col0 + d;
            const int h = (c & 1023) >> 6, dch = c & 63;
            u16 tmp[8];
#pragma unroll
            for (int i = 0; i < 8; ++i) tmp[i] = Cs[(n8 + i) * 137 + d];
            u16* dst = Vtg + (((size_t)(b * H_ + h)) * HD_ + dch) * N_ + nn0 + n8;
            *(uint4*)dst = *(const uint4*)tmp;
        }
    }
}

// ============  out-proj GEMM: C(fp32) = attn * wot^T + bias; tile 128x64  ============
__global__ __launch_bounds__(256, 4) void k_gemm_out(const u16* __restrict__ A,
                                                     const u16* __restrict__ Bt,
                                                     const float* __restrict__ bias,
                                                     float* __restrict__ C) {
    __shared__ u16 smem[16384];
    u16* As = smem;
    u16* Bs = smem + 8192;
    const int t = threadIdx.x;
    const int wave = t >> 6, lane = t & 63;
    const int quad = lane >> 4, l16 = lane & 15;
    const int wm = (wave >> 1) * 64, wn = (wave & 1) * 32;
    const int row0 = blockIdx.x * 128, col0 = blockIdx.y * 64;

    floatx4 acc[4][2] = {};

    const int srow = t >> 3;
    const int scol = (((t & 7) ^ (srow & 7)) * 8);
    const u16* gA = A + (size_t)(row0 + srow) * 1024 + scol;
    const u16* gB = Bt + (size_t)(col0 + srow) * 1024 + scol;
    u16* lA = As + t * 8;
    u16* lB = Bs + t * 8;

    for (int k0 = 0; k0 < 1024; k0 += 64) {
        __syncthreads();
#pragma unroll
        for (int rr = 0; rr < 4; ++rr)
            glds16(gA + (size_t)(rr * 32) * 1024 + k0, lA + rr * 2048);
#pragma unroll
        for (int rr = 0; rr < 2; ++rr)
            glds16(gB + (size_t)(rr * 32) * 1024 + k0, lB + rr * 2048);
        __syncthreads();
#pragma unroll
        for (int c = 0; c < 2; ++c) {
            short8 af[4], bfr[2];
            const int swz = ((4 * c + quad) ^ (l16 & 7)) * 8;
#pragma unroll
            for (int mi = 0; mi < 4; ++mi)
                af[mi] = *(const short8*)(As + (wm + mi * 16 + l16) * 64 + swz);
#pragma unroll
            for (int ni = 0; ni < 2; ++ni)
                bfr[ni] = *(const short8*)(Bs + (wn + ni * 16 + l16) * 64 + swz);
#pragma unroll
            for (int mi = 0; mi < 4; ++mi)
#pragma unroll
                for (int ni = 0; ni < 2; ++ni)
                    acc[mi][ni] = __builtin_amdgcn_mfma_f32_16x16x32_bf16(
                        af[mi], bfr[ni], acc[mi][ni], 0, 0, 0);
        }
    }

    float bv2[2];
#pragma unroll
    for (int ni = 0; ni < 2; ++ni) bv2[ni] = bias[col0 + wn + ni * 16 + l16];

    __syncthreads();
    float* Cf = (float*)smem;
#pragma unroll
    for (int mi = 0; mi < 4; ++mi)
#pragma unroll
        for (int ni = 0; ni < 2; ++ni)
#pragma unroll
            for (int r = 0; r < 4; ++r)
                Cf[(wm + mi * 16 + quad * 4 + r) * 64 + wn + ni * 16 + l16] =
                    acc[mi][ni][r] + bv2[ni];
    __syncthreads();
    const int orow = t >> 4;
    const int oc = (t & 15) * 4;
#pragma unroll
    for (int rr = 0; rr < 8; ++rr) {
        const int row = rr * 16 + orow;
        *(float4*)(C + (size_t)(row0 + row) * 1024 + col0 + oc) =
            *(const float4*)(Cf + row * 64 + oc);
    }
}

// ==========  sliding-window flash attention (no-max softmax, deferred sum)  ==========
// block = (64 q-rows, h, b); staging via global_load_lds + XOR swizzle.
__global__ __launch_bounds__(256, 4) void k_attn(const u16* __restrict__ Qg,
                                                 const u16* __restrict__ Kg,
                                                 const u16* __restrict__ Vtg,
                                                 u16* __restrict__ Og) {
    __shared__ u16 Qs[64 * 64];
    __shared__ u16 Ks[64 * 64];
    __shared__ u16 Vs[64 * 64];
    __shared__ u16 Ps[4 * 16 * 72];
    const int t = threadIdx.x;
    const int wave = t >> 6, lane = t & 63;
    const int quad = lane >> 4, l16 = lane & 15;
    const int q0 = blockIdx.x * 64;
    const int h = blockIdx.y, b = blockIdx.z;
    const size_t bh = (size_t)(b * H_ + h);

    const int srow = t >> 3;                        // 0..31
    const int sch = ((t & 7) ^ (srow & 7)) * 8;     // XOR-swizzled col chunk

    // stage Q (2 glds16/thread), drain, hoist Q fragments into registers
    {
        const u16* qg = Qg + (bh * N_ + q0 + srow) * HD_ + sch;
        glds16(qg, Qs + t * 8);
        glds16(qg + 32 * HD_, Qs + 2048 + t * 8);
    }
    __syncthreads();
    const int swz0 = (quad ^ (l16 & 7)) * 8;
    const int swz1 = ((4 + quad) ^ (l16 & 7)) * 8;
    const short8 aq0 = *(const short8*)(Qs + (wave * 16 + l16) * 64 + swz0);
    const short8 aq1 = *(const short8*)(Qs + (wave * 16 + l16) * 64 + swz1);

    const u16* kg0 = Kg + (bh * N_ + srow) * HD_ + sch;   // + j0*HD_
    const u16* vg0 = Vtg + (bh * HD_ + srow) * N_ + sch;  // + j0

    floatx4 oacc[4] = {};
    float lsum[4] = {0.f, 0.f, 0.f, 0.f};
    const int qrow_base = q0 + wave * 16 + quad * 4;

    // tile range: j0 = q0 - 128 + tt*64 must lie in [0, N)
    const int t0 = (q0 >= 128) ? 0 : ((128 - q0) >> 6);
    const int t1 = min(5, (N_ + 128 - q0) >> 6);

    for (int tt = t0; tt < t1; ++tt) {
        const int j0 = q0 - 128 + tt * 64;
        const bool need_mask = (tt == 0) || (tt == 4);
        __syncthreads();                             // prev tile's K/V reads done
        glds16(kg0 + (size_t)j0 * HD_, Ks + t * 8);
        glds16(kg0 + (size_t)(j0 + 32) * HD_, Ks + 2048 + t * 8);
        glds16(vg0 + j0, Vs + t * 8);
        glds16(vg0 + j0 + 32 * N_, Vs + 2048 + t * 8);
        __syncthreads();                             // drain vmcnt

        floatx4 s[4] = {};
#pragma unroll
        for (int ni = 0; ni < 4; ++ni) {
            short8 bk0 = *(const short8*)(Ks + (ni * 16 + l16) * 64 + swz0);
            short8 bk1 = *(const short8*)(Ks + (ni * 16 + l16) * 64 + swz1);
            s[ni] = __builtin_amdgcn_mfma_f32_16x16x32_bf16(aq0, bk0, s[ni], 0, 0, 0);
            s[ni] = __builtin_amdgcn_mfma_f32_16x16x32_bf16(aq1, bk1, s[ni], 0, 0, 0);
        }
        // exp(s/8); masked -> 0. Inputs bounded so no max-subtraction needed.
        if (need_mask) {
#pragma unroll
            for (int ni = 0; ni < 4; ++ni)
#pragma unroll
                for (int r = 0; r < 4; ++r) {
                    int dj = (j0 + ni * 16 + l16) - (qrow_base + r);
                    bool valid = (dj >= -HALF_W) && (dj <= HALF_W);
                    s[ni][r] = valid ? __expf(s[ni][r] * 0.125f) : 0.f;
                }
        } else {
#pragma unroll
            for (int ni = 0; ni < 4; ++ni)
#pragma unroll
                for (int r = 0; r < 4; ++r) s[ni][r] = __expf(s[ni][r] * 0.125f);
        }
#pragma unroll
        for (int r = 0; r < 4; ++r)
            lsum[r] += s[0][r] + s[1][r] + s[2][r] + s[3][r];
        // P -> wave-private LDS (same-wave write->read, no barrier)
        u16* pw = Ps + wave * 16 * 72;
#pragma unroll
        for (int ni = 0; ni < 4; ++ni)
#pragma unroll
            for (int r = 0; r < 4; ++r)
                pw[(quad * 4 + r) * 72 + ni * 16 + l16] = f2bu(s[ni][r]);
#pragma unroll
        for (int c = 0; c < 2; ++c) {
            short8 pf = *(const short8*)(pw + l16 * 72 + 32 * c + quad * 8);
            const int swz = c ? swz1 : swz0;
#pragma unroll
            for (int ni = 0; ni < 4; ++ni) {
                short8 vf = *(const short8*)(Vs + (ni * 16 + l16) * 64 + swz);
                oacc[ni] = __builtin_amdgcn_mfma_f32_16x16x32_bf16(pf, vf, oacc[ni], 0, 0, 0);
            }
        }
    }
    // one cross-lane reduction at the end
    float linv[4];
#pragma unroll
    for (int r = 0; r < 4; ++r) {
        float v = lsum[r];
        v += __shfl_xor(v, 1); v += __shfl_xor(v, 2);
        v += __shfl_xor(v, 4); v += __shfl_xor(v, 8);
        linv[r] = 1.0f / v;
    }
    u16* outp = Og + ((size_t)b * N_ + q0 + wave * 16 + quad * 4) * INNER_ + h * HD_;
#pragma unroll
    for (int ni = 0; ni < 4; ++ni)
#pragma unroll
        for (int r = 0; r < 4; ++r)
            outp[(size_t)r * INNER_ + ni * 16 + l16] = f2bu(oacc[ni][r] * linv[r]);
}

// =====================  host side  =====================
extern "C" void kernel_launch(void* const* d_in, const int* in_sizes, int n_in,
                              void* d_out, int out_size, void* d_ws, size_t ws_size,
                              hipStream_t stream) {
    const float* x     = (const float*)d_in[0];
    const float* freqs = (const float*)d_in[2];
    const float* Wq    = (const float*)d_in[3];
    const float* bq    = (const float*)d_in[4];
    const float* Wk    = (const float*)d_in[5];
    const float* bk    = (const float*)d_in[6];
    const float* Wv    = (const float*)d_in[7];
    const float* bv    = (const float*)d_in[8];
    const float* Wo    = (const float*)d_in[9];
    const float* bo    = (const float*)d_in[10];

    char* w = (char*)d_ws;
    u16* xb       = (u16*)w;  w += (size_t)4096 * 1024 * 2;
    u16* wqkvt    = (u16*)w;  w += (size_t)3072 * 1024 * 2;
    u16* wot      = (u16*)w;  w += (size_t)1024 * 1024 * 2;
    float* bias_qkv = (float*)w; w += 3072 * 4;
    float* bias_o   = (float*)w; w += 1024 * 4;
    u16* Qb       = (u16*)w;  w += (size_t)B_ * H_ * N_ * HD_ * 2;
    u16* Kb       = (u16*)w;  w += (size_t)B_ * H_ * N_ * HD_ * 2;
    u16* Vtb      = (u16*)w;  w += (size_t)B_ * H_ * N_ * HD_ * 2;
    u16* attn     = (u16*)w;  w += (size_t)4096 * 1024 * 2;

    k_prep<<<2049, 256, 0, stream>>>(x, Wq, Wk, Wv, Wo, bq, bk, bv, bo,
                                     xb, wqkvt, wot, bias_qkv, bias_o);
    k_gemm_qkv<<<dim3(32, 24), 256, 0, stream>>>(xb, wqkvt, bias_qkv, freqs,
                                                 Qb, Kb, Vtb);
    k_attn<<<dim3(32, 16, 2), 256, 0, stream>>>(Qb, Kb, Vtb, attn);
    k_gemm_out<<<dim3(32, 16), 256, 0, stream>>>(attn, wot, bias_o, (float*)d_out);
}